// Round 10
// baseline (1083.866 us; speedup 1.0000x reference)
//
#include <hip/hip_runtime.h>
#include <math.h>

#define T_LEN 4096
#define NBINS 2049          // T/2+1
#define B_SZ 64
#define C_IN 12
#define KM 4
#define FEAT 64

// ---------------------------------------------------------------------------
// LDS XOR swizzle (float4-block granularity): spreads stride-32B reads across
// the 8 four-bank groups. bj -> bj ^ ((bj>>3)&7); stays within 8-block group.
// ---------------------------------------------------------------------------
__device__ __forceinline__ int bswz(int bj) { return bj ^ ((bj >> 3) & 7); }
__device__ __forceinline__ int swz(int j)
{
    int bj = j >> 2;
    return ((bj ^ ((bj >> 3) & 7)) << 2) | (j & 3);
}

// ---------------------------------------------------------------------------
// Gains: the Gauss-Seidel UVMD iteration is linear in X with real
// frequency-only coefficients: u_k = g_k(f) * X(f).
// ---------------------------------------------------------------------------
__global__ void gains_kernel(const float* __restrict__ alpha, // (8,4)
                             const float* __restrict__ tau,   // (8)
                             const float* __restrict__ omega, // (4)
                             float* __restrict__ g)           // (4, NBINS)
{
    int f = blockIdx.x * 256 + threadIdx.x;
    if (f >= NBINS) return;
    float freq = 0.5f * (float)f / 2048.0f;
    float a[4] = {0.f, 0.f, 0.f, 0.f};
    float s = 0.f, lamc = 0.f;
    for (int l = 0; l < 8; ++l) {
        for (int k = 0; k < 4; ++k) {
            float r = 1.f - (s - a[k]) + 0.5f * lamc;
            float d = freq - omega[k];
            float denom = 1.f + alpha[l * 4 + k] * d * d;
            float anew = r / denom;
            s += anew - a[k];
            a[k] = anew;
        }
        lamc += tau[l] * (1.f - s);
    }
    for (int k = 0; k < 4; ++k) g[k * NBINS + f] = a[k];
}

// Twiddle LUT: tw[i] = exp(-i*pi*i/2048), i in [0,2048)
__global__ void twiddle_kernel(float2* __restrict__ tw)
{
    int i = blockIdx.x * 256 + threadIdx.x;
    if (i < 2048) {
        float ang = -(float)M_PI * (float)i / 2048.0f;
        float sn, cs;
        sincosf(ang, &sn, &cs);
        tw[i] = make_float2(cs, sn);
    }
}

__global__ void zero_kernel(float* __restrict__ p, int n)
{
    int i = blockIdx.x * 256 + threadIdx.x;
    if (i < n) p[i] = 0.f;
}

// ---------------------------------------------------------------------------
// Stockham radix-2 stages; twiddles from LUT. syf=+1 fwd, -1 inv (conjugate).
// ---------------------------------------------------------------------------
__device__ inline float2* fft_stages(float2* bufA, float2* bufB,
                                     const float2* __restrict__ tw, float syf)
{
    float2* src = bufA;
    float2* dst = bufB;
    for (int s = 0; s < 12; ++s) {
        int m = 1 << s;
        for (int p = threadIdx.x; p < 2048; p += 512) {
            int j = p >> s;
            int jm = j << s;
            float2 c0 = src[p];
            float2 c1 = src[p + 2048];
            float2 w = tw[jm & 2047];        // j << s
            float cs = w.x, sn = syf * w.y;
            float2 d0 = make_float2(c0.x + c1.x, c0.y + c1.y);
            float2 t1 = make_float2(c0.x - c1.x, c0.y - c1.y);
            float2 d1 = make_float2(cs * t1.x - sn * t1.y, cs * t1.y + sn * t1.x);
            dst[jm + p] = d0;
            dst[jm + p + m] = d1;
        }
        __syncthreads();
        float2* tmp = src; src = dst; dst = tmp;
    }
    return src;   // 12 swaps -> back to bufA
}

// ---------------------------------------------------------------------------
// Forward FFT, 2 real rows (channels c0, c0+1) packed into one complex FFT.
// ---------------------------------------------------------------------------
__global__ __launch_bounds__(512) void fft_fwd_packed(const float* __restrict__ x,
                                                      const float2* __restrict__ tw,
                                                      float2* __restrict__ Xs)
{
    int rp = blockIdx.x;            // 0..383
    int b = rp / 6, c0 = (rp % 6) * 2;
    __shared__ float2 bufA[T_LEN];
    __shared__ float2 bufB[T_LEN];
    for (int t = threadIdx.x; t < T_LEN; t += 512) {
        const float* px = x + ((size_t)b * T_LEN + t) * C_IN + c0;
        bufA[t] = make_float2(px[0], px[1]);
    }
    __syncthreads();
    float2* Z = fft_stages(bufA, bufB, tw, 1.f);
    size_t row = (size_t)b * C_IN + c0;
    for (int f = threadIdx.x; f <= 2048; f += 512) {
        float2 z  = Z[f];
        float2 zm = Z[(T_LEN - f) & (T_LEN - 1)];
        // Xa = (Z + conj(Zm))/2 ; Xb = (Z - conj(Zm))/(2i)
        Xs[row * NBINS + f]       = make_float2(0.5f * (z.x + zm.x), 0.5f * (z.y - zm.y));
        Xs[(row + 1) * NBINS + f] = make_float2(0.5f * (z.y + zm.y), 0.5f * (zm.x - z.x));
    }
}

// ---------------------------------------------------------------------------
// Inverse FFT for mode k, 2 rows packed: Z = g_k*(Xa + i*Xb) (both Hermitian)
// -> complex IFFT -> re = mode row c0, im = row c0+1.
// ---------------------------------------------------------------------------
__global__ __launch_bounds__(512) void fft_inv_packed(const float2* __restrict__ Xs,
                                                      const float* __restrict__ g,
                                                      const float2* __restrict__ tw,
                                                      float* __restrict__ mode,
                                                      int k)
{
    int rp = blockIdx.x;
    int b = rp / 6, c0 = (rp % 6) * 2;
    size_t rowa = (size_t)b * C_IN + c0;
    __shared__ float2 bufA[T_LEN];
    __shared__ float2 bufB[T_LEN];
    const float* gk = g + k * NBINS;
    for (int f = threadIdx.x; f < T_LEN; f += 512) {
        int fe = (f <= 2048) ? f : (T_LEN - f);
        float2 A  = Xs[rowa * NBINS + fe];
        float2 Bv = Xs[(rowa + 1) * NBINS + fe];
        float gv = gk[fe];
        if (f > 2048) { A.y = -A.y; Bv.y = -Bv.y; }   // Hermitian extension
        bufA[f] = make_float2(gv * (A.x - Bv.y), gv * (A.y + Bv.x));
    }
    __syncthreads();
    float2* z = fft_stages(bufA, bufB, tw, -1.f);
    const float invn = 1.f / (float)T_LEN;
    for (int t = threadIdx.x; t < T_LEN; t += 512) {
        mode[rowa * T_LEN + t]       = z[t].x * invn;
        mode[(rowa + 1) * T_LEN + t] = z[t].y * invn;
    }
}

// ---------------------------------------------------------------------------
// Register-tiled conv1d + BN(eval) + ReLU (+ optional mean over T).
// Block = 256 threads = (OUT/8 o-groups) x (TGRPS t-groups); each thread
// computes an 8(o) x 8(t) register tile (fits VGPR budget: ~64 acc + 16 xr).
// Input tile XOR-swizzled in LDS; weights staged [c*KW+d][o] with o-major
// (conflict-free) stores; c-chunked to stay under 64 KB.
// ---------------------------------------------------------------------------
template<int CIN, int KW, int OUT, int TILE, int CCHUNK, bool MEAN>
__global__ __launch_bounds__(256) void conv_tiled(
    const float* __restrict__ in,    // (B, CIN, T)
    const float* __restrict__ W,     // (OUT, CIN, KW)
    const float* __restrict__ bias,
    const float* __restrict__ gamma,
    const float* __restrict__ beta,
    float* __restrict__ out,         // (B, OUT, T) or feats (B, 256)
    int k_slot)
{
    constexpr int OGRPS = OUT / 8;
    constexpr int TGRPS = 256 / OGRPS;
    constexpr int PAD = (KW - 1) / 2;
    constexpr int OFF = 4 - PAD;
    constexpr int ROWW = TILE + 16;       // halo 8 both sides
    constexpr int NCHUNK = CIN / CCHUNK;
    static_assert(TGRPS * 8 == TILE, "tile mismatch");
    static_assert(!MEAN || TGRPS == 32, "mean reduce assumes 32-lane groups");

    __shared__ float xs[CCHUNK][ROWW];
    __shared__ float wt[CCHUNK * KW * OUT];   // [c*KW+d][o]

    const int b = blockIdx.y;
    const int tile0 = blockIdx.x * TILE;
    const int tid = threadIdx.x;
    const int ogrp = tid / TGRPS;
    const int tgrp = tid % TGRPS;
    const int t0l = tgrp * 8;
    const int o0 = ogrp * 8;

    float acc[8][8];
#pragma unroll
    for (int i = 0; i < 8; ++i)
#pragma unroll
        for (int j = 0; j < 8; ++j) acc[i][j] = 0.f;

    const bool interior = (tile0 >= 8) && (tile0 + TILE + 8 <= T_LEN);

    for (int ch = 0; ch < NCHUNK; ++ch) {
        if (ch) __syncthreads();
        const float* src = in + ((size_t)b * CIN + ch * CCHUNK) * T_LEN;
        if (interior) {
            for (int i = tid; i < CCHUNK * (ROWW / 4); i += 256) {
                int c = i / (ROWW / 4), j = i % (ROWW / 4);
                ((float4*)&xs[c][0])[bswz(j)] =
                    ((const float4*)(src + (size_t)c * T_LEN + tile0 - 8))[j];
            }
        } else {
            for (int i = tid; i < CCHUNK * ROWW; i += 256) {
                int c = i / ROWW, j = i % ROWW;
                int t = tile0 - 8 + j;
                xs[c][swz(j)] = (t >= 0 && t < T_LEN) ? src[(size_t)c * T_LEN + t] : 0.f;
            }
        }
        // o-major weight staging: consecutive lanes -> consecutive banks
        // (proven by r9: conflicts 2.06e7 -> 6.9e6 with this pattern).
        constexpr int WTOT = CCHUNK * KW * OUT;
        for (int i = tid; i < WTOT; i += 256) {
            int o = i % OUT;
            int cd = i / OUT;                 // c*KW + d
            int c = cd / KW, d = cd % KW;
            wt[cd * OUT + o] = W[((size_t)o * CIN + ch * CCHUNK + c) * KW + d];
        }
        __syncthreads();

        for (int c = 0; c < CCHUNK; ++c) {
            float xr[16];
            const float4* xp4 = (const float4*)&xs[c][0];
            const int bb = (t0l >> 2) + 1;            // (t0l + 4) / 4
            float4 a0 = xp4[bswz(bb)];
            float4 a1 = xp4[bswz(bb + 1)];
            float4 a2 = xp4[bswz(bb + 2)];
            float4 a3 = xp4[bswz(bb + 3)];
            xr[0] = a0.x;  xr[1] = a0.y;  xr[2] = a0.z;  xr[3] = a0.w;
            xr[4] = a1.x;  xr[5] = a1.y;  xr[6] = a1.z;  xr[7] = a1.w;
            xr[8] = a2.x;  xr[9] = a2.y;  xr[10] = a2.z; xr[11] = a2.w;
            xr[12] = a3.x; xr[13] = a3.y; xr[14] = a3.z; xr[15] = a3.w;
#pragma unroll
            for (int d = 0; d < KW; ++d) {
                const float4* wp = (const float4*)&wt[(c * KW + d) * OUT + o0];
                float4 w0 = wp[0], w1 = wp[1];
                float wv[8] = {w0.x, w0.y, w0.z, w0.w, w1.x, w1.y, w1.z, w1.w};
#pragma unroll
                for (int os = 0; os < 8; ++os)
#pragma unroll
                    for (int tt = 0; tt < 8; ++tt)
                        acc[os][tt] = fmaf(wv[os], xr[tt + d + OFF], acc[os][tt]);
            }
        }
    }

    const float rs = 1.f / sqrtf(1.f + 1e-5f);
    if (!MEAN) {
#pragma unroll
        for (int os = 0; os < 8; ++os) {
            int o = o0 + os;
            float sc = gamma[o] * rs;
            float bb = fmaf(bias[o], sc, beta[o]);
            float4 v0, v1;
            v0.x = fmaxf(fmaf(acc[os][0], sc, bb), 0.f);
            v0.y = fmaxf(fmaf(acc[os][1], sc, bb), 0.f);
            v0.z = fmaxf(fmaf(acc[os][2], sc, bb), 0.f);
            v0.w = fmaxf(fmaf(acc[os][3], sc, bb), 0.f);
            v1.x = fmaxf(fmaf(acc[os][4], sc, bb), 0.f);
            v1.y = fmaxf(fmaf(acc[os][5], sc, bb), 0.f);
            v1.z = fmaxf(fmaf(acc[os][6], sc, bb), 0.f);
            v1.w = fmaxf(fmaf(acc[os][7], sc, bb), 0.f);
            float* dst = out + ((size_t)b * OUT + o) * T_LEN + tile0 + t0l;
            ((float4*)dst)[0] = v0;
            ((float4*)dst)[1] = v1;
        }
    } else {
#pragma unroll
        for (int os = 0; os < 8; ++os) {
            int o = o0 + os;
            float sc = gamma[o] * rs;
            float bb = fmaf(bias[o], sc, beta[o]);
            float s = 0.f;
#pragma unroll
            for (int tt = 0; tt < 8; ++tt)
                s += fmaxf(fmaf(acc[os][tt], sc, bb), 0.f);
            // reduce across the 32 t-group lanes (contiguous half-wave)
#pragma unroll
            for (int off = 1; off < 32; off <<= 1)
                s += __shfl_xor(s, off, 64);
            if (tgrp == 0)
                atomicAdd(&out[b * (KM * FEAT) + k_slot * FEAT + o], s * (1.f / (float)T_LEN));
        }
    }
}

// ---------------------------------------------------------------------------
// Classifier: feats(B,256) -> relu(@Wc1.T+bc1) -> @Wc2.T+bc2 -> (B,10)
// ---------------------------------------------------------------------------
__global__ __launch_bounds__(128) void classifier_kernel(const float* __restrict__ feats,
                                                         const float* __restrict__ Wc1, // (128,256)
                                                         const float* __restrict__ bc1,
                                                         const float* __restrict__ Wc2, // (10,128)
                                                         const float* __restrict__ bc2,
                                                         float* __restrict__ out)
{
    int b = blockIdx.x;
    int j = threadIdx.x;
    __shared__ float h[128];
    float acc = bc1[j];
    const float* fb = feats + b * 256;
    for (int i = 0; i < 256; ++i) acc = fmaf(fb[i], Wc1[j * 256 + i], acc);
    h[j] = fmaxf(acc, 0.f);
    __syncthreads();
    if (j < 10) {
        float acc2 = bc2[j];
        for (int i = 0; i < 128; ++i) acc2 = fmaf(h[i], Wc2[j * 128 + i], acc2);
        out[b * 10 + j] = acc2;
    }
}

extern "C" void kernel_launch(void* const* d_in, const int* in_sizes, int n_in,
                              void* d_out, int out_size, void* d_ws, size_t ws_size,
                              hipStream_t stream)
{
    const float* x     = (const float*)d_in[0];
    const float* alpha = (const float*)d_in[1];
    const float* tau   = (const float*)d_in[2];
    const float* omega = (const float*)d_in[3];
    const float* W1    = (const float*)d_in[4];
    const float* b1    = (const float*)d_in[5];
    const float* g1    = (const float*)d_in[6];
    const float* be1   = (const float*)d_in[7];
    const float* W2    = (const float*)d_in[8];
    const float* b2    = (const float*)d_in[9];
    const float* g2    = (const float*)d_in[10];
    const float* be2   = (const float*)d_in[11];
    const float* W3    = (const float*)d_in[12];
    const float* b3    = (const float*)d_in[13];
    const float* g3    = (const float*)d_in[14];
    const float* be3   = (const float*)d_in[15];
    const float* Wc1   = (const float*)d_in[16];
    const float* bc1   = (const float*)d_in[17];
    const float* Wc2   = (const float*)d_in[18];
    const float* bc2   = (const float*)d_in[19];

    const int NROWS = B_SZ * C_IN;   // 768
    float* ws = (float*)d_ws;
    float2* tw   = (float2*)ws;                            // 2048 float2
    float* g     = ws + 4096;                              // 4*2049
    float2* Xs   = (float2*)(ws + 4096 + 4 * NBINS);       // 768*2049 c
    float* mode  = ws + 4096 + 4 * NBINS + (size_t)NROWS * NBINS * 2;
    float* h1    = mode + (size_t)NROWS * T_LEN;           // 64*32*4096
    float* h2    = h1 + (size_t)B_SZ * 32 * T_LEN;         // 64*64*4096
    float* feats = h2 + (size_t)B_SZ * 64 * T_LEN;         // 64*256

    gains_kernel<<<(NBINS + 255) / 256, 256, 0, stream>>>(alpha, tau, omega, g);
    twiddle_kernel<<<8, 256, 0, stream>>>(tw);
    zero_kernel<<<64, 256, 0, stream>>>(feats, B_SZ * KM * FEAT);
    fft_fwd_packed<<<NROWS / 2, 512, 0, stream>>>(x, tw, Xs);

    for (int k = 0; k < KM; ++k) {
        fft_inv_packed<<<NROWS / 2, 512, 0, stream>>>(Xs, g, tw, mode, k);
        // conv1: 12 -> 32, kw=7, 8o x 8t, TILE=512
        conv_tiled<12, 7, 32, 512, 12, false><<<dim3(T_LEN / 512, B_SZ), 256, 0, stream>>>(
            mode, W1 + k * 32 * 12 * 7, b1 + k * 32, g1 + k * 32, be1 + k * 32, h1, 0);
        // conv2: 32 -> 64, kw=5, 8o x 8t, TILE=256, c-chunk 16
        conv_tiled<32, 5, 64, 256, 16, false><<<dim3(T_LEN / 256, B_SZ), 256, 0, stream>>>(
            h1, W2 + k * 64 * 32 * 5, b2 + k * 64, g2 + k * 64, be2 + k * 64, h2, 0);
        // conv3 + mean: 64 -> 64, kw=3, 8o x 8t, TILE=256, c-chunk 16
        conv_tiled<64, 3, 64, 256, 16, true><<<dim3(T_LEN / 256, B_SZ), 256, 0, stream>>>(
            h2, W3 + k * 64 * 64 * 3, b3 + k * 64, g3 + k * 64, be3 + k * 64, feats, k);
    }

    classifier_kernel<<<B_SZ, 128, 0, stream>>>(feats, Wc1, bc1, Wc2, bc2, (float*)d_out);
}

// Round 11
// 775.050 us; speedup vs baseline: 1.3984x; 1.3984x over previous
//
#include <hip/hip_runtime.h>
#include <math.h>

#define T_LEN 4096
#define NBINS 2049          // T/2+1
#define B_SZ 64
#define C_IN 12
#define KM 4
#define FEAT 64

typedef __attribute__((ext_vector_type(8))) short short8v;   // 8 bf16 (4 VGPRs)
typedef __attribute__((ext_vector_type(4))) float floatx4;

// fp32 -> bf16 with RNE (manual; no API dependency)
__device__ __forceinline__ unsigned short f2bf(float f)
{
    unsigned int u = __float_as_uint(f);
    u += 0x7FFFu + ((u >> 16) & 1u);
    return (unsigned short)(u >> 16);
}

// ---------------------------------------------------------------------------
// LDS XOR swizzle (float4-block granularity) for the fp32 conv path.
// ---------------------------------------------------------------------------
__device__ __forceinline__ int bswz(int bj) { return bj ^ ((bj >> 3) & 7); }
__device__ __forceinline__ int swz(int j)
{
    int bj = j >> 2;
    return ((bj ^ ((bj >> 3) & 7)) << 2) | (j & 3);
}

// ---------------------------------------------------------------------------
// Gains: UVMD Gauss-Seidel is linear in X with real freq-only coefficients.
// ---------------------------------------------------------------------------
__global__ void gains_kernel(const float* __restrict__ alpha,
                             const float* __restrict__ tau,
                             const float* __restrict__ omega,
                             float* __restrict__ g)
{
    int f = blockIdx.x * 256 + threadIdx.x;
    if (f >= NBINS) return;
    float freq = 0.5f * (float)f / 2048.0f;
    float a[4] = {0.f, 0.f, 0.f, 0.f};
    float s = 0.f, lamc = 0.f;
    for (int l = 0; l < 8; ++l) {
        for (int k = 0; k < 4; ++k) {
            float r = 1.f - (s - a[k]) + 0.5f * lamc;
            float d = freq - omega[k];
            float denom = 1.f + alpha[l * 4 + k] * d * d;
            float anew = r / denom;
            s += anew - a[k];
            a[k] = anew;
        }
        lamc += tau[l] * (1.f - s);
    }
    for (int k = 0; k < 4; ++k) g[k * NBINS + f] = a[k];
}

__global__ void twiddle_kernel(float2* __restrict__ tw)
{
    int i = blockIdx.x * 256 + threadIdx.x;
    if (i < 2048) {
        float ang = -(float)M_PI * (float)i / 2048.0f;
        float sn, cs;
        sincosf(ang, &sn, &cs);
        tw[i] = make_float2(cs, sn);
    }
}

__global__ void zero_kernel(float* __restrict__ p, int n)
{
    int i = blockIdx.x * 256 + threadIdx.x;
    if (i < n) p[i] = 0.f;
}

// ---------------------------------------------------------------------------
// Weight prep for conv3 MFMA: W3(K,64o,64c,3d) fp32 ->
// Wp[k][d][o][c] bf16 with 16B-block swizzle (blk ^= o&7) baked in.
// ---------------------------------------------------------------------------
__global__ void prep_w3(const float* __restrict__ W3, unsigned short* __restrict__ Wp)
{
    int i = blockIdx.x * 256 + threadIdx.x;
    if (i >= KM * 3 * 64 * 64) return;
    int c = i & 63;
    int o = (i >> 6) & 63;
    int kd = i >> 12;            // k*3 + d
    int d = kd % 3, k = kd / 3;
    float v = W3[(((size_t)k * 64 + o) * 64 + c) * 3 + d];
    int blk = (c >> 3) ^ (o & 7);
    Wp[(size_t)k * (3 * 64 * 64) + (d * 64 + o) * 64 + blk * 8 + (c & 7)] = f2bf(v);
}

// ---------------------------------------------------------------------------
// Stockham radix-2 stages; twiddles from LUT. syf=+1 fwd, -1 inv (conjugate).
// ---------------------------------------------------------------------------
__device__ inline float2* fft_stages(float2* bufA, float2* bufB,
                                     const float2* __restrict__ tw, float syf)
{
    float2* src = bufA;
    float2* dst = bufB;
    for (int s = 0; s < 12; ++s) {
        int m = 1 << s;
        for (int p = threadIdx.x; p < 2048; p += 512) {
            int j = p >> s;
            int jm = j << s;
            float2 c0 = src[p];
            float2 c1 = src[p + 2048];
            float2 w = tw[jm & 2047];
            float cs = w.x, sn = syf * w.y;
            float2 d0 = make_float2(c0.x + c1.x, c0.y + c1.y);
            float2 t1 = make_float2(c0.x - c1.x, c0.y - c1.y);
            float2 d1 = make_float2(cs * t1.x - sn * t1.y, cs * t1.y + sn * t1.x);
            dst[jm + p] = d0;
            dst[jm + p + m] = d1;
        }
        __syncthreads();
        float2* tmp = src; src = dst; dst = tmp;
    }
    return src;
}

__global__ __launch_bounds__(512) void fft_fwd_packed(const float* __restrict__ x,
                                                      const float2* __restrict__ tw,
                                                      float2* __restrict__ Xs)
{
    int rp = blockIdx.x;
    int b = rp / 6, c0 = (rp % 6) * 2;
    __shared__ float2 bufA[T_LEN];
    __shared__ float2 bufB[T_LEN];
    for (int t = threadIdx.x; t < T_LEN; t += 512) {
        const float* px = x + ((size_t)b * T_LEN + t) * C_IN + c0;
        bufA[t] = make_float2(px[0], px[1]);
    }
    __syncthreads();
    float2* Z = fft_stages(bufA, bufB, tw, 1.f);
    size_t row = (size_t)b * C_IN + c0;
    for (int f = threadIdx.x; f <= 2048; f += 512) {
        float2 z  = Z[f];
        float2 zm = Z[(T_LEN - f) & (T_LEN - 1)];
        Xs[row * NBINS + f]       = make_float2(0.5f * (z.x + zm.x), 0.5f * (z.y - zm.y));
        Xs[(row + 1) * NBINS + f] = make_float2(0.5f * (z.y + zm.y), 0.5f * (zm.x - z.x));
    }
}

__global__ __launch_bounds__(512) void fft_inv_packed(const float2* __restrict__ Xs,
                                                      const float* __restrict__ g,
                                                      const float2* __restrict__ tw,
                                                      float* __restrict__ mode,
                                                      int k)
{
    int rp = blockIdx.x;
    int b = rp / 6, c0 = (rp % 6) * 2;
    size_t rowa = (size_t)b * C_IN + c0;
    __shared__ float2 bufA[T_LEN];
    __shared__ float2 bufB[T_LEN];
    const float* gk = g + k * NBINS;
    for (int f = threadIdx.x; f < T_LEN; f += 512) {
        int fe = (f <= 2048) ? f : (T_LEN - f);
        float2 A  = Xs[rowa * NBINS + fe];
        float2 Bv = Xs[(rowa + 1) * NBINS + fe];
        float gv = gk[fe];
        if (f > 2048) { A.y = -A.y; Bv.y = -Bv.y; }
        bufA[f] = make_float2(gv * (A.x - Bv.y), gv * (A.y + Bv.x));
    }
    __syncthreads();
    float2* z = fft_stages(bufA, bufB, tw, -1.f);
    const float invn = 1.f / (float)T_LEN;
    for (int t = threadIdx.x; t < T_LEN; t += 512) {
        mode[rowa * T_LEN + t]       = z[t].x * invn;
        mode[(rowa + 1) * T_LEN + t] = z[t].y * invn;
    }
}

// ---------------------------------------------------------------------------
// Register-tiled fp32 conv1d + BN + ReLU (r5-measured structure).
// OUTBF=false: write fp32 (B,OUT,T). OUTBF=true: repack to bf16 [t][OUT]
// global layout with 16B-block swizzle (blk ^= t&7) baked in, via LDS.
// ---------------------------------------------------------------------------
template<int CIN, int KW, int OUT, int TILE, int CCHUNK, bool OUTBF>
__global__ __launch_bounds__(256) void conv_tiled(
    const float* __restrict__ in,
    const float* __restrict__ W,
    const float* __restrict__ bias,
    const float* __restrict__ gamma,
    const float* __restrict__ beta,
    float* __restrict__ out)
{
    constexpr int OGRPS = OUT / 8;
    constexpr int TGRPS = 256 / OGRPS;
    constexpr int PAD = (KW - 1) / 2;
    constexpr int OFF = 4 - PAD;
    constexpr int ROWW = TILE + 16;
    constexpr int NCHUNK = CIN / CCHUNK;
    static_assert(TGRPS * 8 == TILE, "tile mismatch");

    constexpr size_t XSB = (size_t)CCHUNK * ROWW * 4;
    constexpr size_t WTB = (size_t)CCHUNK * KW * OUT * 4;
    constexpr size_t RPB = OUTBF ? (size_t)TILE * OUT * 2 : 0;
    constexpr size_t SMEM = (XSB + WTB) > RPB ? (XSB + WTB) : RPB;
    __shared__ __align__(16) char smem[SMEM];
    float* xsf = (float*)smem;
    float* wt  = (float*)(smem + XSB);

    const int b = blockIdx.y;
    const int tile0 = blockIdx.x * TILE;
    const int tid = threadIdx.x;
    const int ogrp = tid / TGRPS;
    const int tgrp = tid % TGRPS;
    const int t0l = tgrp * 8;
    const int o0 = ogrp * 8;

    float acc[8][8];
#pragma unroll
    for (int i = 0; i < 8; ++i)
#pragma unroll
        for (int j = 0; j < 8; ++j) acc[i][j] = 0.f;

    const bool interior = (tile0 >= 8) && (tile0 + TILE + 8 <= T_LEN);

    for (int ch = 0; ch < NCHUNK; ++ch) {
        if (ch) __syncthreads();
        const float* src = in + ((size_t)b * CIN + ch * CCHUNK) * T_LEN;
        if (interior) {
            for (int i = tid; i < CCHUNK * (ROWW / 4); i += 256) {
                int c = i / (ROWW / 4), j = i % (ROWW / 4);
                ((float4*)(xsf + c * ROWW))[bswz(j)] =
                    ((const float4*)(src + (size_t)c * T_LEN + tile0 - 8))[j];
            }
        } else {
            for (int i = tid; i < CCHUNK * ROWW; i += 256) {
                int c = i / ROWW, j = i % ROWW;
                int t = tile0 - 8 + j;
                xsf[c * ROWW + swz(j)] = (t >= 0 && t < T_LEN) ? src[(size_t)c * T_LEN + t] : 0.f;
            }
        }
        constexpr int WTOT = CCHUNK * KW * OUT;
        for (int i = tid; i < WTOT; i += 256) {
            int o = i / (CCHUNK * KW);
            int rem = i % (CCHUNK * KW);
            int c = rem / KW, d = rem % KW;
            wt[(c * KW + d) * OUT + o] = W[((size_t)o * CIN + ch * CCHUNK + c) * KW + d];
        }
        __syncthreads();

        for (int c = 0; c < CCHUNK; ++c) {
            float xr[16];
            const float4* xp4 = (const float4*)(xsf + c * ROWW);
            const int bb = (t0l >> 2) + 1;
            float4 a0 = xp4[bswz(bb)];
            float4 a1 = xp4[bswz(bb + 1)];
            float4 a2 = xp4[bswz(bb + 2)];
            float4 a3 = xp4[bswz(bb + 3)];
            xr[0] = a0.x;  xr[1] = a0.y;  xr[2] = a0.z;  xr[3] = a0.w;
            xr[4] = a1.x;  xr[5] = a1.y;  xr[6] = a1.z;  xr[7] = a1.w;
            xr[8] = a2.x;  xr[9] = a2.y;  xr[10] = a2.z; xr[11] = a2.w;
            xr[12] = a3.x; xr[13] = a3.y; xr[14] = a3.z; xr[15] = a3.w;
#pragma unroll
            for (int d = 0; d < KW; ++d) {
                const float4* wp = (const float4*)&wt[(c * KW + d) * OUT + o0];
                float4 w0 = wp[0], w1 = wp[1];
                float wv[8] = {w0.x, w0.y, w0.z, w0.w, w1.x, w1.y, w1.z, w1.w};
#pragma unroll
                for (int os = 0; os < 8; ++os)
#pragma unroll
                    for (int tt = 0; tt < 8; ++tt)
                        acc[os][tt] = fmaf(wv[os], xr[tt + d + OFF], acc[os][tt]);
            }
        }
    }

    const float rs = 1.f / sqrtf(1.f + 1e-5f);
    // BN + ReLU in place
#pragma unroll
    for (int os = 0; os < 8; ++os) {
        int o = o0 + os;
        float sc = gamma[o] * rs;
        float bb = fmaf(bias[o], sc, beta[o]);
#pragma unroll
        for (int tt = 0; tt < 8; ++tt)
            acc[os][tt] = fmaxf(fmaf(acc[os][tt], sc, bb), 0.f);
    }

    if (!OUTBF) {
#pragma unroll
        for (int os = 0; os < 8; ++os) {
            int o = o0 + os;
            float* dst = out + ((size_t)b * OUT + o) * T_LEN + tile0 + t0l;
            float4 v0 = make_float4(acc[os][0], acc[os][1], acc[os][2], acc[os][3]);
            float4 v1 = make_float4(acc[os][4], acc[os][5], acc[os][6], acc[os][7]);
            ((float4*)dst)[0] = v0;
            ((float4*)dst)[1] = v1;
        }
    } else {
        // repack to bf16 [t][OUT] swizzled in LDS, then flat coalesced store
        __syncthreads();
        char* rep = smem;
#pragma unroll
        for (int r = 0; r < 8; ++r) {
            int rp = (r + tgrp) & 7;           // lane-rotated row to avoid bank conflicts
            int t_loc = t0l + rp;              // (tile0 + t_loc) & 7 == rp
            short8v pk;
#pragma unroll
            for (int os = 0; os < 8; ++os)
                pk[os] = (short)f2bf(acc[os][rp]);
            int blk = (o0 >> 3) ^ rp;
            *(short8v*)(rep + (size_t)t_loc * (OUT * 2) + blk * 16) = pk;
        }
        __syncthreads();
        unsigned short* gout = (unsigned short*)out;
        const size_t base = ((size_t)b * T_LEN + tile0) * OUT * 2;  // bytes
        constexpr int CH16 = TILE * OUT * 2 / 16;
        for (int i = tid; i < CH16; i += 256)
            *(float4*)((char*)gout + base + (size_t)i * 16) = *(float4*)(rep + (size_t)i * 16);
    }
}

// ---------------------------------------------------------------------------
// conv3 via MFMA bf16 16x16x32: input h2bf [b][t][64] bf16 (swizzled),
// weights Wp [d][o][c] bf16 (swizzled). Block = 128t x 64o for one b;
// 4 waves each own 32t x 64o; weights live in 24 register fragments.
// Fused BN+ReLU+mean -> feats atomicAdd.
// D = A*B: A(m=t): row=l&15, k=8*(l>>4)+j. B(n=o): col=l&15, k same.
// D: col(o)=l&15, row(t)=4*(l>>4)+reg.
// ---------------------------------------------------------------------------
__global__ __launch_bounds__(256) void conv3_mfma(
    const unsigned short* __restrict__ h2bf,
    const unsigned short* __restrict__ Wp,
    const float* __restrict__ bias,
    const float* __restrict__ gamma,
    const float* __restrict__ beta,
    float* __restrict__ feats,
    int k_slot)
{
    __shared__ __align__(16) char smem[16640 + 24576];  // X: 130*128B, W: 24576B
    char* Xl = smem;
    char* Wl = smem + 16640;

    const int b = blockIdx.y;
    const int t0 = blockIdx.x * 128;
    const int tid = threadIdx.x;

    // stage X tile rows t0-1 .. t0+128 (fully contiguous in global; swizzle baked)
    for (int i = tid; i < 1040; i += 256) {         // 130 rows * 8 chunks of 16B
        int row = i >> 3;
        int tg = t0 - 1 + row;
        float4 v = make_float4(0.f, 0.f, 0.f, 0.f);
        if (tg >= 0 && tg < T_LEN)
            v = *(const float4*)((const char*)h2bf + ((size_t)b * T_LEN + tg) * 128 + (i & 7) * 16);
        *(float4*)(Xl + (size_t)i * 16) = v;
    }
    // stage weights (flat 24576B copy)
    for (int i = tid; i < 1536; i += 256)
        *(float4*)(Wl + (size_t)i * 16) = *(const float4*)((const char*)Wp + (size_t)i * 16);
    __syncthreads();

    const int w  = tid >> 6;
    const int l  = tid & 63;
    const int lo = l & 15;
    const int hi = l >> 4;

    // load all 24 weight fragments into registers: Bf[d*2+ch][n]
    short8v Bf[6][4];
#pragma unroll
    for (int d = 0; d < 3; ++d)
#pragma unroll
        for (int ch = 0; ch < 2; ++ch)
#pragma unroll
            for (int n = 0; n < 4; ++n) {
                int o = n * 16 + lo;
                int blk = (4 * ch + hi) ^ (o & 7);
                Bf[d * 2 + ch][n] =
                    *(const short8v*)(Wl + (size_t)(d * 64 + o) * 128 + blk * 16);
            }

    floatx4 acc[2][4];
#pragma unroll
    for (int m = 0; m < 2; ++m)
#pragma unroll
        for (int n = 0; n < 4; ++n)
            acc[m][n] = (floatx4){0.f, 0.f, 0.f, 0.f};

#pragma unroll
    for (int d = 0; d < 3; ++d)
#pragma unroll
        for (int ch = 0; ch < 2; ++ch) {
#pragma unroll
            for (int m = 0; m < 2; ++m) {
                int tl = w * 32 + m * 16 + lo + d;           // LDS row (t_loc)
                int blk = (4 * ch + hi) ^ ((tl - 1) & 7);    // global-t swizzle key
                short8v Af = *(const short8v*)(Xl + (size_t)tl * 128 + blk * 16);
#pragma unroll
                for (int n = 0; n < 4; ++n)
                    acc[m][n] = __builtin_amdgcn_mfma_f32_16x16x32_bf16(
                        Af, Bf[d * 2 + ch][n], acc[m][n], 0, 0, 0);
            }
        }

    // epilogue: BN + ReLU + sum over t, reduce across hi-groups, atomicAdd
    const float rs = 1.f / sqrtf(1.f + 1e-5f);
#pragma unroll
    for (int n = 0; n < 4; ++n) {
        int o = n * 16 + lo;
        float sc = gamma[o] * rs;
        float bb = fmaf(bias[o], sc, beta[o]);
        float s = 0.f;
#pragma unroll
        for (int m = 0; m < 2; ++m)
#pragma unroll
            for (int r = 0; r < 4; ++r)
                s += fmaxf(fmaf(acc[m][n][r], sc, bb), 0.f);
        s += __shfl_xor(s, 16, 64);
        s += __shfl_xor(s, 32, 64);
        if (hi == 0)
            atomicAdd(&feats[b * (KM * FEAT) + k_slot * FEAT + o], s * (1.f / (float)T_LEN));
    }
}

// ---------------------------------------------------------------------------
// Classifier: feats(B,256) -> relu(@Wc1.T+bc1) -> @Wc2.T+bc2 -> (B,10)
// ---------------------------------------------------------------------------
__global__ __launch_bounds__(128) void classifier_kernel(const float* __restrict__ feats,
                                                         const float* __restrict__ Wc1,
                                                         const float* __restrict__ bc1,
                                                         const float* __restrict__ Wc2,
                                                         const float* __restrict__ bc2,
                                                         float* __restrict__ out)
{
    int b = blockIdx.x;
    int j = threadIdx.x;
    __shared__ float h[128];
    float acc = bc1[j];
    const float* fb = feats + b * 256;
    for (int i = 0; i < 256; ++i) acc = fmaf(fb[i], Wc1[j * 256 + i], acc);
    h[j] = fmaxf(acc, 0.f);
    __syncthreads();
    if (j < 10) {
        float acc2 = bc2[j];
        for (int i = 0; i < 128; ++i) acc2 = fmaf(h[i], Wc2[j * 128 + i], acc2);
        out[b * 10 + j] = acc2;
    }
}

extern "C" void kernel_launch(void* const* d_in, const int* in_sizes, int n_in,
                              void* d_out, int out_size, void* d_ws, size_t ws_size,
                              hipStream_t stream)
{
    const float* x     = (const float*)d_in[0];
    const float* alpha = (const float*)d_in[1];
    const float* tau   = (const float*)d_in[2];
    const float* omega = (const float*)d_in[3];
    const float* W1    = (const float*)d_in[4];
    const float* b1    = (const float*)d_in[5];
    const float* g1    = (const float*)d_in[6];
    const float* be1   = (const float*)d_in[7];
    const float* W2    = (const float*)d_in[8];
    const float* b2    = (const float*)d_in[9];
    const float* g2    = (const float*)d_in[10];
    const float* be2   = (const float*)d_in[11];
    const float* W3    = (const float*)d_in[12];
    const float* b3    = (const float*)d_in[13];
    const float* g3    = (const float*)d_in[14];
    const float* be3   = (const float*)d_in[15];
    const float* Wc1   = (const float*)d_in[16];
    const float* bc1   = (const float*)d_in[17];
    const float* Wc2   = (const float*)d_in[18];
    const float* bc2   = (const float*)d_in[19];

    const int NROWS = B_SZ * C_IN;   // 768
    float* ws = (float*)d_ws;
    float2* tw   = (float2*)ws;                            // 2048 float2
    float* g     = ws + 4096;                              // 4*2049
    float2* Xs   = (float2*)(ws + 4096 + 4 * NBINS);       // 768*2049 complex
    float* mode  = ws + 4096 + 4 * NBINS + (size_t)NROWS * NBINS * 2;
    float* h1    = mode + (size_t)NROWS * T_LEN;           // 64*32*4096 fp32
    float* h2    = h1 + (size_t)B_SZ * 32 * T_LEN;         // reused: bf16 [b][t][64]
    float* feats = h2 + (size_t)B_SZ * 64 * T_LEN;         // 64*256
    unsigned short* Wp = (unsigned short*)(feats + B_SZ * KM * FEAT); // 49152 bf16
    unsigned short* h2bf = (unsigned short*)h2;

    gains_kernel<<<(NBINS + 255) / 256, 256, 0, stream>>>(alpha, tau, omega, g);
    twiddle_kernel<<<8, 256, 0, stream>>>(tw);
    zero_kernel<<<64, 256, 0, stream>>>(feats, B_SZ * KM * FEAT);
    prep_w3<<<(KM * 3 * 64 * 64 + 255) / 256, 256, 0, stream>>>(W3, Wp);
    fft_fwd_packed<<<NROWS / 2, 512, 0, stream>>>(x, tw, Xs);

    for (int k = 0; k < KM; ++k) {
        fft_inv_packed<<<NROWS / 2, 512, 0, stream>>>(Xs, g, tw, mode, k);
        // conv1: 12 -> 32, kw=7, fp32 out (r5-measured config)
        conv_tiled<12, 7, 32, 512, 12, false><<<dim3(T_LEN / 512, B_SZ), 256, 0, stream>>>(
            mode, W1 + k * 32 * 12 * 7, b1 + k * 32, g1 + k * 32, be1 + k * 32, h1);
        // conv2: 32 -> 64, kw=5, fp32 compute, bf16 [t][64] swizzled out
        conv_tiled<32, 5, 64, 256, 16, true><<<dim3(T_LEN / 256, B_SZ), 256, 0, stream>>>(
            h1, W2 + k * 64 * 32 * 5, b2 + k * 64, g2 + k * 64, be2 + k * 64, (float*)h2bf);
        // conv3 + mean: MFMA bf16
        conv3_mfma<<<dim3(T_LEN / 128, B_SZ), 256, 0, stream>>>(
            h2bf, Wp + (size_t)k * 3 * 64 * 64, b3 + k * 64, g3 + k * 64, be3 + k * 64,
            feats, k);
    }

    classifier_kernel<<<B_SZ, 128, 0, stream>>>(feats, Wc1, bc1, Wc2, bc2, (float*)d_out);
}

// Round 12
// 456.828 us; speedup vs baseline: 2.3726x; 1.6966x over previous
//
#include <hip/hip_runtime.h>
#include <math.h>

#define T_LEN 4096
#define NBINS 2049          // T/2+1
#define B_SZ 64
#define C_IN 12
#define KM 4
#define FEAT 64

typedef __attribute__((ext_vector_type(8))) short short8v;   // 8 bf16 (4 VGPRs)
typedef __attribute__((ext_vector_type(4))) float floatx4;

// fp32 -> bf16 with RNE
__device__ __forceinline__ unsigned short f2bf(float f)
{
    unsigned int u = __float_as_uint(f);
    u += 0x7FFFu + ((u >> 16) & 1u);
    return (unsigned short)(u >> 16);
}

// LDS XOR swizzle for the fp32 conv path (float4-block granularity)
__device__ __forceinline__ int bswz(int bj) { return bj ^ ((bj >> 3) & 7); }
__device__ __forceinline__ int swz(int j)
{
    int bj = j >> 2;
    return ((bj ^ ((bj >> 3) & 7)) << 2) | (j & 3);
}

// ---------------------------------------------------------------------------
// Gains: UVMD Gauss-Seidel is linear in X with real freq-only coefficients.
// ---------------------------------------------------------------------------
__global__ void gains_kernel(const float* __restrict__ alpha,
                             const float* __restrict__ tau,
                             const float* __restrict__ omega,
                             float* __restrict__ g)
{
    int f = blockIdx.x * 256 + threadIdx.x;
    if (f >= NBINS) return;
    float freq = 0.5f * (float)f / 2048.0f;
    float a[4] = {0.f, 0.f, 0.f, 0.f};
    float s = 0.f, lamc = 0.f;
    for (int l = 0; l < 8; ++l) {
        for (int k = 0; k < 4; ++k) {
            float r = 1.f - (s - a[k]) + 0.5f * lamc;
            float d = freq - omega[k];
            float denom = 1.f + alpha[l * 4 + k] * d * d;
            float anew = r / denom;
            s += anew - a[k];
            a[k] = anew;
        }
        lamc += tau[l] * (1.f - s);
    }
    for (int k = 0; k < 4; ++k) g[k * NBINS + f] = a[k];
}

__global__ void twiddle_kernel(float2* __restrict__ tw)
{
    int i = blockIdx.x * 256 + threadIdx.x;
    if (i < 2048) {
        float ang = -(float)M_PI * (float)i / 2048.0f;
        float sn, cs;
        sincosf(ang, &sn, &cs);
        tw[i] = make_float2(cs, sn);
    }
}

__global__ void zero_kernel(float* __restrict__ p, int n)
{
    int i = blockIdx.x * 256 + threadIdx.x;
    if (i < n) p[i] = 0.f;
}

// ---------------------------------------------------------------------------
// Weight prep conv3: W3(K,64o,64c,3d) -> Wp3[k][d][o-row swizzled] bf16.
// Row o = 128B, chunk blk = (c>>3) ^ (o&7).
// ---------------------------------------------------------------------------
__global__ void prep_w3(const float* __restrict__ W3, unsigned short* __restrict__ Wp)
{
    int i = blockIdx.x * 256 + threadIdx.x;
    if (i >= KM * 3 * 64 * 64) return;
    int c = i & 63;
    int o = (i >> 6) & 63;
    int kd = i >> 12;
    int d = kd % 3, k = kd / 3;
    float v = W3[(((size_t)k * 64 + o) * 64 + c) * 3 + d];
    int blk = (c >> 3) ^ (o & 7);
    Wp[(size_t)k * (3 * 64 * 64) + (d * 64 + o) * 64 + blk * 8 + (c & 7)] = f2bf(v);
}

// ---------------------------------------------------------------------------
// Weight prep conv2: W2(K,64o,32c,5d) -> Wp2[k][d][superrow-swizzled o x c].
// Superrow = 2 o-rows = 128B; chunk q = (o&1)*4 + (c>>3); q' = q ^ ((o>>1)&7).
// ---------------------------------------------------------------------------
__global__ void prep_w2(const float* __restrict__ W2, unsigned short* __restrict__ Wp2)
{
    int i = blockIdx.x * 256 + threadIdx.x;
    if (i >= KM * 5 * 64 * 32) return;
    int c = i & 31;
    int o = (i >> 5) & 63;
    int kd = i >> 11;
    int d = kd % 5, k = kd / 5;
    float v = W2[(((size_t)k * 64 + o) * 32 + c) * 5 + d];
    int sr = o >> 1;
    int q = (o & 1) * 4 + (c >> 3);
    int qp = q ^ (sr & 7);
    Wp2[(size_t)(k * 5 + d) * 2048 + sr * 64 + qp * 8 + (c & 7)] = f2bf(v);
}

// ---------------------------------------------------------------------------
// Stockham radix-2 stages; twiddles from LUT. syf=+1 fwd, -1 inv.
// ---------------------------------------------------------------------------
__device__ inline float2* fft_stages(float2* bufA, float2* bufB,
                                     const float2* __restrict__ tw, float syf)
{
    float2* src = bufA;
    float2* dst = bufB;
    for (int s = 0; s < 12; ++s) {
        int m = 1 << s;
        for (int p = threadIdx.x; p < 2048; p += 512) {
            int j = p >> s;
            int jm = j << s;
            float2 c0 = src[p];
            float2 c1 = src[p + 2048];
            float2 w = tw[jm & 2047];
            float cs = w.x, sn = syf * w.y;
            float2 d0 = make_float2(c0.x + c1.x, c0.y + c1.y);
            float2 t1 = make_float2(c0.x - c1.x, c0.y - c1.y);
            float2 d1 = make_float2(cs * t1.x - sn * t1.y, cs * t1.y + sn * t1.x);
            dst[jm + p] = d0;
            dst[jm + p + m] = d1;
        }
        __syncthreads();
        float2* tmp = src; src = dst; dst = tmp;
    }
    return src;
}

__global__ __launch_bounds__(512) void fft_fwd_packed(const float* __restrict__ x,
                                                      const float2* __restrict__ tw,
                                                      float2* __restrict__ Xs)
{
    int rp = blockIdx.x;
    int b = rp / 6, c0 = (rp % 6) * 2;
    __shared__ float2 bufA[T_LEN];
    __shared__ float2 bufB[T_LEN];
    for (int t = threadIdx.x; t < T_LEN; t += 512) {
        const float* px = x + ((size_t)b * T_LEN + t) * C_IN + c0;
        bufA[t] = make_float2(px[0], px[1]);
    }
    __syncthreads();
    float2* Z = fft_stages(bufA, bufB, tw, 1.f);
    size_t row = (size_t)b * C_IN + c0;
    for (int f = threadIdx.x; f <= 2048; f += 512) {
        float2 z  = Z[f];
        float2 zm = Z[(T_LEN - f) & (T_LEN - 1)];
        Xs[row * NBINS + f]       = make_float2(0.5f * (z.x + zm.x), 0.5f * (z.y - zm.y));
        Xs[(row + 1) * NBINS + f] = make_float2(0.5f * (z.y + zm.y), 0.5f * (zm.x - z.x));
    }
}

__global__ __launch_bounds__(512) void fft_inv_packed(const float2* __restrict__ Xs,
                                                      const float* __restrict__ g,
                                                      const float2* __restrict__ tw,
                                                      float* __restrict__ mode,
                                                      int k)
{
    int rp = blockIdx.x;
    int b = rp / 6, c0 = (rp % 6) * 2;
    size_t rowa = (size_t)b * C_IN + c0;
    __shared__ float2 bufA[T_LEN];
    __shared__ float2 bufB[T_LEN];
    const float* gk = g + k * NBINS;
    for (int f = threadIdx.x; f < T_LEN; f += 512) {
        int fe = (f <= 2048) ? f : (T_LEN - f);
        float2 A  = Xs[rowa * NBINS + fe];
        float2 Bv = Xs[(rowa + 1) * NBINS + fe];
        float gv = gk[fe];
        if (f > 2048) { A.y = -A.y; Bv.y = -Bv.y; }
        bufA[f] = make_float2(gv * (A.x - Bv.y), gv * (A.y + Bv.x));
    }
    __syncthreads();
    float2* z = fft_stages(bufA, bufB, tw, -1.f);
    const float invn = 1.f / (float)T_LEN;
    for (int t = threadIdx.x; t < T_LEN; t += 512) {
        mode[rowa * T_LEN + t]       = z[t].x * invn;
        mode[(rowa + 1) * T_LEN + t] = z[t].y * invn;
    }
}

// ---------------------------------------------------------------------------
// conv1: fp32 register-tiled (r5-measured structure) + BN + ReLU, output
// repacked to bf16 [t][32] superrow-swizzled global layout for conv2 MFMA.
// ---------------------------------------------------------------------------
template<int CIN, int KW, int OUT, int TILE, int CCHUNK>
__global__ __launch_bounds__(256) void conv1_fp32(
    const float* __restrict__ in,
    const float* __restrict__ W,
    const float* __restrict__ bias,
    const float* __restrict__ gamma,
    const float* __restrict__ beta,
    unsigned short* __restrict__ outbf)      // [b] planes of T*64 bytes
{
    constexpr int OGRPS = OUT / 8;           // 4
    constexpr int TGRPS = 256 / OGRPS;       // 64
    constexpr int PAD = (KW - 1) / 2;
    constexpr int OFF = 4 - PAD;
    constexpr int ROWW = TILE + 16;
    constexpr int NCHUNK = CIN / CCHUNK;
    static_assert(TGRPS * 8 == TILE, "tile mismatch");
    static_assert(OUT == 32, "repack assumes 32 channels");

    constexpr size_t XSB = (size_t)CCHUNK * ROWW * 4;
    constexpr size_t WTB = (size_t)CCHUNK * KW * OUT * 4;
    constexpr size_t RPB = (size_t)TILE * OUT * 2;       // 32768
    constexpr size_t SMEM = (XSB + WTB) > RPB ? (XSB + WTB) : RPB;
    __shared__ __align__(16) char smem[SMEM];
    float* xsf = (float*)smem;
    float* wt  = (float*)(smem + XSB);

    const int b = blockIdx.y;
    const int tile0 = blockIdx.x * TILE;
    const int tid = threadIdx.x;
    const int ogrp = tid / TGRPS;
    const int tgrp = tid % TGRPS;
    const int t0l = tgrp * 8;
    const int o0 = ogrp * 8;

    float acc[8][8];
#pragma unroll
    for (int i = 0; i < 8; ++i)
#pragma unroll
        for (int j = 0; j < 8; ++j) acc[i][j] = 0.f;

    const bool interior = (tile0 >= 8) && (tile0 + TILE + 8 <= T_LEN);

    for (int ch = 0; ch < NCHUNK; ++ch) {
        if (ch) __syncthreads();
        const float* src = in + ((size_t)b * CIN + ch * CCHUNK) * T_LEN;
        if (interior) {
            for (int i = tid; i < CCHUNK * (ROWW / 4); i += 256) {
                int c = i / (ROWW / 4), j = i % (ROWW / 4);
                ((float4*)(xsf + c * ROWW))[bswz(j)] =
                    ((const float4*)(src + (size_t)c * T_LEN + tile0 - 8))[j];
            }
        } else {
            for (int i = tid; i < CCHUNK * ROWW; i += 256) {
                int c = i / ROWW, j = i % ROWW;
                int t = tile0 - 8 + j;
                xsf[c * ROWW + swz(j)] = (t >= 0 && t < T_LEN) ? src[(size_t)c * T_LEN + t] : 0.f;
            }
        }
        constexpr int WTOT = CCHUNK * KW * OUT;
        for (int i = tid; i < WTOT; i += 256) {
            int o = i / (CCHUNK * KW);
            int rem = i % (CCHUNK * KW);
            int c = rem / KW, d = rem % KW;
            wt[(c * KW + d) * OUT + o] = W[((size_t)o * CIN + ch * CCHUNK + c) * KW + d];
        }
        __syncthreads();

        for (int c = 0; c < CCHUNK; ++c) {
            float xr[16];
            const float4* xp4 = (const float4*)(xsf + c * ROWW);
            const int bb = (t0l >> 2) + 1;
            float4 a0 = xp4[bswz(bb)];
            float4 a1 = xp4[bswz(bb + 1)];
            float4 a2 = xp4[bswz(bb + 2)];
            float4 a3 = xp4[bswz(bb + 3)];
            xr[0] = a0.x;  xr[1] = a0.y;  xr[2] = a0.z;  xr[3] = a0.w;
            xr[4] = a1.x;  xr[5] = a1.y;  xr[6] = a1.z;  xr[7] = a1.w;
            xr[8] = a2.x;  xr[9] = a2.y;  xr[10] = a2.z; xr[11] = a2.w;
            xr[12] = a3.x; xr[13] = a3.y; xr[14] = a3.z; xr[15] = a3.w;
#pragma unroll
            for (int d = 0; d < KW; ++d) {
                const float4* wp = (const float4*)&wt[(c * KW + d) * OUT + o0];
                float4 w0 = wp[0], w1 = wp[1];
                float wv[8] = {w0.x, w0.y, w0.z, w0.w, w1.x, w1.y, w1.z, w1.w};
#pragma unroll
                for (int os = 0; os < 8; ++os)
#pragma unroll
                    for (int tt = 0; tt < 8; ++tt)
                        acc[os][tt] = fmaf(wv[os], xr[tt + d + OFF], acc[os][tt]);
            }
        }
    }

    const float rs = 1.f / sqrtf(1.f + 1e-5f);
#pragma unroll
    for (int os = 0; os < 8; ++os) {
        int o = o0 + os;
        float sc = gamma[o] * rs;
        float bb = fmaf(bias[o], sc, beta[o]);
#pragma unroll
        for (int tt = 0; tt < 8; ++tt)
            acc[os][tt] = fmaxf(fmaf(acc[os][tt], sc, bb), 0.f);
    }

    // repack: bf16 [t][32] superrow-swizzled (tile0 mult of 512 -> local keys)
    __syncthreads();
    char* rep = smem;
#pragma unroll
    for (int r = 0; r < 8; ++r) {
        int rp = (r + tgrp) & 7;
        int t_loc = t0l + rp;
        short8v pk;
#pragma unroll
        for (int os = 0; os < 8; ++os)
            pk[os] = (short)f2bf(acc[os][rp]);
        int sr = t_loc >> 1;
        int q = (t_loc & 1) * 4 + ogrp;
        int qp = q ^ (sr & 7);
        *(short8v*)(rep + (size_t)sr * 128 + qp * 16) = pk;
    }
    __syncthreads();
    char* dst = (char*)outbf + (size_t)b * (T_LEN * 64) + (size_t)tile0 * 64;
    for (int i = tid; i < (int)(RPB / 16); i += 256)
        *(float4*)(dst + (size_t)i * 16) = *(float4*)(rep + (size_t)i * 16);
}

// ---------------------------------------------------------------------------
// conv2 via MFMA bf16 16x16x32: input h1bf [b][t][32] superrow-swizzled,
// weights Wp2 [d][superrow o x c]. Block = 128t x 64o; 4 waves x (32t x 64o).
// K = 32 (one fragment per d). Output h2bf [t][64] (conv3 format).
// ---------------------------------------------------------------------------
__global__ __launch_bounds__(256) void conv2_mfma(
    const unsigned short* __restrict__ h1bf,
    const unsigned short* __restrict__ Wp2,    // 5 planes of 4096B
    const float* __restrict__ bias,
    const float* __restrict__ gamma,
    const float* __restrict__ beta,
    unsigned short* __restrict__ h2bf)
{
    __shared__ __align__(16) char smem[9216 + 20480 + 16384];
    char* Xl  = smem;              // 72 superrows * 128B, t in [t0-8, t0+136)
    char* Wl  = smem + 9216;       // 20480B
    char* rep = smem + 9216 + 20480;

    const int b = blockIdx.y;
    const int t0 = blockIdx.x * 128;
    const int tid = threadIdx.x;
    const char* src = (const char*)h1bf + (size_t)b * (T_LEN * 64);

    // stage X: 576 x 16B chunks; zero-fill chunks whose t is out of range
    for (int i = tid; i < 576; i += 256) {
        int sr_loc = i >> 3;
        int qp = i & 7;
        int key = (sr_loc + 4) & 7;            // ((t0-8)/2 + sr_loc) & 7
        int q = qp ^ key;
        int t = (t0 - 8) + sr_loc * 2 + (q >> 2);
        float4 v = make_float4(0.f, 0.f, 0.f, 0.f);
        if (t >= 0 && t < T_LEN)
            v = *(const float4*)(src + (ptrdiff_t)(t0 - 8) * 64 + (size_t)i * 16);
        *(float4*)(Xl + (size_t)i * 16) = v;
    }
    for (int i = tid; i < 1280; i += 256)
        *(float4*)(Wl + (size_t)i * 16) = *(const float4*)((const char*)Wp2 + (size_t)i * 16);
    __syncthreads();

    const int w  = tid >> 6;
    const int l  = tid & 63;
    const int lo = l & 15;
    const int hi = l >> 4;

    short8v Bf[5][4];
#pragma unroll
    for (int d = 0; d < 5; ++d)
#pragma unroll
        for (int n = 0; n < 4; ++n) {
            int o = n * 16 + lo;
            int sr = o >> 1;
            int q = (o & 1) * 4 + hi;
            int qp = q ^ (sr & 7);
            Bf[d][n] = *(const short8v*)(Wl + (size_t)d * 4096 + sr * 128 + qp * 16);
        }

    floatx4 acc[2][4];
#pragma unroll
    for (int m = 0; m < 2; ++m)
#pragma unroll
        for (int n = 0; n < 4; ++n)
            acc[m][n] = (floatx4){0.f, 0.f, 0.f, 0.f};

#pragma unroll
    for (int d = 0; d < 5; ++d)
#pragma unroll
        for (int m = 0; m < 2; ++m) {
            int tl = w * 32 + m * 16 + lo + d + 6;   // t - (t0-8)
            int sr = tl >> 1;
            int q = (tl & 1) * 4 + hi;
            int qp = q ^ ((sr + 4) & 7);
            short8v Af = *(const short8v*)(Xl + (size_t)sr * 128 + qp * 16);
#pragma unroll
            for (int n = 0; n < 4; ++n)
                acc[m][n] = __builtin_amdgcn_mfma_f32_16x16x32_bf16(
                    Af, Bf[d][n], acc[m][n], 0, 0, 0);
        }

    // epilogue: BN + ReLU, scatter to rep [128t][64o] in conv3 swizzle format
    const float rs = 1.f / sqrtf(1.f + 1e-5f);
#pragma unroll
    for (int n = 0; n < 4; ++n) {
        int o = n * 16 + lo;
        float sc = gamma[o] * rs;
        float bb = fmaf(bias[o], sc, beta[o]);
        int cq = o >> 3;
#pragma unroll
        for (int m = 0; m < 2; ++m)
#pragma unroll
            for (int r = 0; r < 4; ++r) {
                float v = fmaxf(fmaf(acc[m][n][r], sc, bb), 0.f);
                int trow = w * 32 + m * 16 + 4 * hi + r;
                *(unsigned short*)(rep + (size_t)trow * 128 +
                                   ((cq ^ (trow & 7)) * 16) + (o & 7) * 2) = f2bf(v);
            }
    }
    __syncthreads();
    char* dst = (char*)h2bf + (size_t)b * (T_LEN * 128) + (size_t)t0 * 128;
    for (int i = tid; i < 1024; i += 256)
        *(float4*)(dst + (size_t)i * 16) = *(float4*)(rep + (size_t)i * 16);
}

// ---------------------------------------------------------------------------
// conv3 via MFMA bf16 (verified r11): input h2bf [b][t][64] swizzled,
// fused BN+ReLU+mean -> feats atomicAdd.
// ---------------------------------------------------------------------------
__global__ __launch_bounds__(256) void conv3_mfma(
    const unsigned short* __restrict__ h2bf,
    const unsigned short* __restrict__ Wp,
    const float* __restrict__ bias,
    const float* __restrict__ gamma,
    const float* __restrict__ beta,
    float* __restrict__ feats,
    int k_slot)
{
    __shared__ __align__(16) char smem[16640 + 24576];
    char* Xl = smem;
    char* Wl = smem + 16640;

    const int b = blockIdx.y;
    const int t0 = blockIdx.x * 128;
    const int tid = threadIdx.x;

    for (int i = tid; i < 1040; i += 256) {
        int row = i >> 3;
        int tg = t0 - 1 + row;
        float4 v = make_float4(0.f, 0.f, 0.f, 0.f);
        if (tg >= 0 && tg < T_LEN)
            v = *(const float4*)((const char*)h2bf + ((size_t)b * T_LEN + tg) * 128 + (i & 7) * 16);
        *(float4*)(Xl + (size_t)i * 16) = v;
    }
    for (int i = tid; i < 1536; i += 256)
        *(float4*)(Wl + (size_t)i * 16) = *(const float4*)((const char*)Wp + (size_t)i * 16);
    __syncthreads();

    const int w  = tid >> 6;
    const int l  = tid & 63;
    const int lo = l & 15;
    const int hi = l >> 4;

    short8v Bf[6][4];
#pragma unroll
    for (int d = 0; d < 3; ++d)
#pragma unroll
        for (int ch = 0; ch < 2; ++ch)
#pragma unroll
            for (int n = 0; n < 4; ++n) {
                int o = n * 16 + lo;
                int blk = (4 * ch + hi) ^ (o & 7);
                Bf[d * 2 + ch][n] =
                    *(const short8v*)(Wl + (size_t)(d * 64 + o) * 128 + blk * 16);
            }

    floatx4 acc[2][4];
#pragma unroll
    for (int m = 0; m < 2; ++m)
#pragma unroll
        for (int n = 0; n < 4; ++n)
            acc[m][n] = (floatx4){0.f, 0.f, 0.f, 0.f};

#pragma unroll
    for (int d = 0; d < 3; ++d)
#pragma unroll
        for (int ch = 0; ch < 2; ++ch) {
#pragma unroll
            for (int m = 0; m < 2; ++m) {
                int tl = w * 32 + m * 16 + lo + d;
                int blk = (4 * ch + hi) ^ ((tl - 1) & 7);
                short8v Af = *(const short8v*)(Xl + (size_t)tl * 128 + blk * 16);
#pragma unroll
                for (int n = 0; n < 4; ++n)
                    acc[m][n] = __builtin_amdgcn_mfma_f32_16x16x32_bf16(
                        Af, Bf[d * 2 + ch][n], acc[m][n], 0, 0, 0);
            }
        }

    const float rs = 1.f / sqrtf(1.f + 1e-5f);
#pragma unroll
    for (int n = 0; n < 4; ++n) {
        int o = n * 16 + lo;
        float sc = gamma[o] * rs;
        float bb = fmaf(bias[o], sc, beta[o]);
        float s = 0.f;
#pragma unroll
        for (int m = 0; m < 2; ++m)
#pragma unroll
            for (int r = 0; r < 4; ++r)
                s += fmaxf(fmaf(acc[m][n][r], sc, bb), 0.f);
        s += __shfl_xor(s, 16, 64);
        s += __shfl_xor(s, 32, 64);
        if (hi == 0)
            atomicAdd(&feats[b * (KM * FEAT) + k_slot * FEAT + o], s * (1.f / (float)T_LEN));
    }
}

// ---------------------------------------------------------------------------
// Classifier
// ---------------------------------------------------------------------------
__global__ __launch_bounds__(128) void classifier_kernel(const float* __restrict__ feats,
                                                         const float* __restrict__ Wc1,
                                                         const float* __restrict__ bc1,
                                                         const float* __restrict__ Wc2,
                                                         const float* __restrict__ bc2,
                                                         float* __restrict__ out)
{
    int b = blockIdx.x;
    int j = threadIdx.x;
    __shared__ float h[128];
    float acc = bc1[j];
    const float* fb = feats + b * 256;
    for (int i = 0; i < 256; ++i) acc = fmaf(fb[i], Wc1[j * 256 + i], acc);
    h[j] = fmaxf(acc, 0.f);
    __syncthreads();
    if (j < 10) {
        float acc2 = bc2[j];
        for (int i = 0; i < 128; ++i) acc2 = fmaf(h[i], Wc2[j * 128 + i], acc2);
        out[b * 10 + j] = acc2;
    }
}

extern "C" void kernel_launch(void* const* d_in, const int* in_sizes, int n_in,
                              void* d_out, int out_size, void* d_ws, size_t ws_size,
                              hipStream_t stream)
{
    const float* x     = (const float*)d_in[0];
    const float* alpha = (const float*)d_in[1];
    const float* tau   = (const float*)d_in[2];
    const float* omega = (const float*)d_in[3];
    const float* W1    = (const float*)d_in[4];
    const float* b1    = (const float*)d_in[5];
    const float* g1    = (const float*)d_in[6];
    const float* be1   = (const float*)d_in[7];
    const float* W2    = (const float*)d_in[8];
    const float* b2    = (const float*)d_in[9];
    const float* g2    = (const float*)d_in[10];
    const float* be2   = (const float*)d_in[11];
    const float* W3    = (const float*)d_in[12];
    const float* b3    = (const float*)d_in[13];
    const float* g3    = (const float*)d_in[14];
    const float* be3   = (const float*)d_in[15];
    const float* Wc1   = (const float*)d_in[16];
    const float* bc1   = (const float*)d_in[17];
    const float* Wc2   = (const float*)d_in[18];
    const float* bc2   = (const float*)d_in[19];

    const int NROWS = B_SZ * C_IN;   // 768
    float* ws = (float*)d_ws;
    float2* tw   = (float2*)ws;                                  // 4096 floats
    float* g     = ws + 4096;                                    // 8196 floats
    float2* Xs   = (float2*)(ws + 4096 + 4 * NBINS);             // 3147264 floats
    float* mode  = ws + 4096 + 4 * NBINS + (size_t)NROWS * NBINS * 2;
    unsigned short* h1bf = (unsigned short*)(mode + (size_t)NROWS * T_LEN);
    unsigned short* h2bf = h1bf + (size_t)B_SZ * T_LEN * 32;
    float* feats = (float*)(h2bf + (size_t)B_SZ * T_LEN * 64);
    unsigned short* Wp3 = (unsigned short*)(feats + B_SZ * KM * FEAT);
    unsigned short* Wp2 = Wp3 + KM * 3 * 64 * 64;

    gains_kernel<<<(NBINS + 255) / 256, 256, 0, stream>>>(alpha, tau, omega, g);
    twiddle_kernel<<<8, 256, 0, stream>>>(tw);
    zero_kernel<<<64, 256, 0, stream>>>(feats, B_SZ * KM * FEAT);
    prep_w3<<<(KM * 3 * 64 * 64 + 255) / 256, 256, 0, stream>>>(W3, Wp3);
    prep_w2<<<(KM * 5 * 64 * 32 + 255) / 256, 256, 0, stream>>>(W2, Wp2);
    fft_fwd_packed<<<NROWS / 2, 512, 0, stream>>>(x, tw, Xs);

    for (int k = 0; k < KM; ++k) {
        fft_inv_packed<<<NROWS / 2, 512, 0, stream>>>(Xs, g, tw, mode, k);
        conv1_fp32<12, 7, 32, 512, 12><<<dim3(T_LEN / 512, B_SZ), 256, 0, stream>>>(
            mode, W1 + k * 32 * 12 * 7, b1 + k * 32, g1 + k * 32, be1 + k * 32, h1bf);
        conv2_mfma<<<dim3(T_LEN / 128, B_SZ), 256, 0, stream>>>(
            h1bf, Wp2 + (size_t)k * 5 * 2048, b2 + k * 64, g2 + k * 64, be2 + k * 64, h2bf);
        conv3_mfma<<<dim3(T_LEN / 128, B_SZ), 256, 0, stream>>>(
            h2bf, Wp3 + (size_t)k * 3 * 64 * 64, b3 + k * 64, g3 + k * 64, be3 + k * 64,
            feats, k);
    }

    classifier_kernel<<<B_SZ, 128, 0, stream>>>(feats, Wc1, bc1, Wc2, bc2, (float*)d_out);
}

// Round 13
// 333.421 us; speedup vs baseline: 3.2507x; 1.3701x over previous
//
#include <hip/hip_runtime.h>
#include <math.h>

#define T_LEN 4096
#define NBINS 2049          // T/2+1
#define B_SZ 64
#define C_IN 12
#define KM 4
#define FEAT 64

typedef __attribute__((ext_vector_type(8))) short short8v;   // 8 bf16 (4 VGPRs)
typedef __attribute__((ext_vector_type(4))) float floatx4;

// fp32 -> bf16 with RNE
__device__ __forceinline__ unsigned short f2bf(float f)
{
    unsigned int u = __float_as_uint(f);
    u += 0x7FFFu + ((u >> 16) & 1u);
    return (unsigned short)(u >> 16);
}

// ---------------------------------------------------------------------------
// Gains: UVMD Gauss-Seidel is linear in X with real freq-only coefficients.
// ---------------------------------------------------------------------------
__global__ void gains_kernel(const float* __restrict__ alpha,
                             const float* __restrict__ tau,
                             const float* __restrict__ omega,
                             float* __restrict__ g)
{
    int f = blockIdx.x * 256 + threadIdx.x;
    if (f >= NBINS) return;
    float freq = 0.5f * (float)f / 2048.0f;
    float a[4] = {0.f, 0.f, 0.f, 0.f};
    float s = 0.f, lamc = 0.f;
    for (int l = 0; l < 8; ++l) {
        for (int k = 0; k < 4; ++k) {
            float r = 1.f - (s - a[k]) + 0.5f * lamc;
            float d = freq - omega[k];
            float denom = 1.f + alpha[l * 4 + k] * d * d;
            float anew = r / denom;
            s += anew - a[k];
            a[k] = anew;
        }
        lamc += tau[l] * (1.f - s);
    }
    for (int k = 0; k < 4; ++k) g[k * NBINS + f] = a[k];
}

__global__ void twiddle_kernel(float2* __restrict__ tw)
{
    int i = blockIdx.x * 256 + threadIdx.x;
    if (i < 2048) {
        float ang = -(float)M_PI * (float)i / 2048.0f;
        float sn, cs;
        sincosf(ang, &sn, &cs);
        tw[i] = make_float2(cs, sn);
    }
}

__global__ void zero_kernel(float* __restrict__ p, int n)
{
    int i = blockIdx.x * 256 + threadIdx.x;
    if (i < n) p[i] = 0.f;
}

__global__ void zero4_kernel(float4* __restrict__ p, int n)
{
    int i = blockIdx.x * 256 + threadIdx.x;
    if (i < n) p[i] = make_float4(0.f, 0.f, 0.f, 0.f);
}

// ---------------------------------------------------------------------------
// Weight prep conv1: W1(K,32o,12c,7d) -> Wp1[k][dpair][o][kidx] bf16.
// MFMA K-fragment: kidx = 8*hi+j; d = dpair*2 + (kidx>>4); c = kidx&15.
// Zero-pad d=7 and c>=12.
// ---------------------------------------------------------------------------
__global__ void prep_w1(const float* __restrict__ W1, unsigned short* __restrict__ Wp1)
{
    int i = blockIdx.x * 256 + threadIdx.x;
    if (i >= KM * 4 * 32 * 32) return;      // 16384
    int kidx  = i & 31;
    int o     = (i >> 5) & 31;
    int dpair = (i >> 10) & 3;
    int k     = i >> 12;
    int d = dpair * 2 + (kidx >> 4);
    int c = kidx & 15;
    float v = (d < 7 && c < 12) ? W1[(((size_t)k * 32 + o) * 12 + c) * 7 + d] : 0.f;
    Wp1[(size_t)k * 4096 + dpair * 1024 + o * 32 + kidx] = f2bf(v);
}

// ---------------------------------------------------------------------------
// Weight prep conv2 (verified r12): superrow = 2 o-rows = 128B.
// ---------------------------------------------------------------------------
__global__ void prep_w2(const float* __restrict__ W2, unsigned short* __restrict__ Wp2)
{
    int i = blockIdx.x * 256 + threadIdx.x;
    if (i >= KM * 5 * 64 * 32) return;
    int c = i & 31;
    int o = (i >> 5) & 63;
    int kd = i >> 11;
    int d = kd % 5, k = kd / 5;
    float v = W2[(((size_t)k * 64 + o) * 32 + c) * 5 + d];
    int sr = o >> 1;
    int q = (o & 1) * 4 + (c >> 3);
    int qp = q ^ (sr & 7);
    Wp2[(size_t)(k * 5 + d) * 2048 + sr * 64 + qp * 8 + (c & 7)] = f2bf(v);
}

// ---------------------------------------------------------------------------
// Weight prep conv3 (verified r11).
// ---------------------------------------------------------------------------
__global__ void prep_w3(const float* __restrict__ W3, unsigned short* __restrict__ Wp)
{
    int i = blockIdx.x * 256 + threadIdx.x;
    if (i >= KM * 3 * 64 * 64) return;
    int c = i & 63;
    int o = (i >> 6) & 63;
    int kd = i >> 12;
    int d = kd % 3, k = kd / 3;
    float v = W3[(((size_t)k * 64 + o) * 64 + c) * 3 + d];
    int blk = (c >> 3) ^ (o & 7);
    Wp[(size_t)k * (3 * 64 * 64) + (d * 64 + o) * 64 + blk * 8 + (c & 7)] = f2bf(v);
}

// ---------------------------------------------------------------------------
// Stockham radix-2 stages; twiddles from LUT. syf=+1 fwd, -1 inv.
// ---------------------------------------------------------------------------
__device__ inline float2* fft_stages(float2* bufA, float2* bufB,
                                     const float2* __restrict__ tw, float syf)
{
    float2* src = bufA;
    float2* dst = bufB;
    for (int s = 0; s < 12; ++s) {
        int m = 1 << s;
        for (int p = threadIdx.x; p < 2048; p += 512) {
            int j = p >> s;
            int jm = j << s;
            float2 c0 = src[p];
            float2 c1 = src[p + 2048];
            float2 w = tw[jm & 2047];
            float cs = w.x, sn = syf * w.y;
            float2 d0 = make_float2(c0.x + c1.x, c0.y + c1.y);
            float2 t1 = make_float2(c0.x - c1.x, c0.y - c1.y);
            float2 d1 = make_float2(cs * t1.x - sn * t1.y, cs * t1.y + sn * t1.x);
            dst[jm + p] = d0;
            dst[jm + p + m] = d1;
        }
        __syncthreads();
        float2* tmp = src; src = dst; dst = tmp;
    }
    return src;
}

__global__ __launch_bounds__(512) void fft_fwd_packed(const float* __restrict__ x,
                                                      const float2* __restrict__ tw,
                                                      float2* __restrict__ Xs)
{
    int rp = blockIdx.x;
    int b = rp / 6, c0 = (rp % 6) * 2;
    __shared__ float2 bufA[T_LEN];
    __shared__ float2 bufB[T_LEN];
    for (int t = threadIdx.x; t < T_LEN; t += 512) {
        const float* px = x + ((size_t)b * T_LEN + t) * C_IN + c0;
        bufA[t] = make_float2(px[0], px[1]);
    }
    __syncthreads();
    float2* Z = fft_stages(bufA, bufB, tw, 1.f);
    size_t row = (size_t)b * C_IN + c0;
    for (int f = threadIdx.x; f <= 2048; f += 512) {
        float2 z  = Z[f];
        float2 zm = Z[(T_LEN - f) & (T_LEN - 1)];
        Xs[row * NBINS + f]       = make_float2(0.5f * (z.x + zm.x), 0.5f * (z.y - zm.y));
        Xs[(row + 1) * NBINS + f] = make_float2(0.5f * (z.y + zm.y), 0.5f * (zm.x - z.x));
    }
}

// ---------------------------------------------------------------------------
// Inverse FFT, k-batched (blockIdx.y = k). Output: bf16 mode planes
// [k][b][t][16c] with superrow swizzle (sr = t>>2, q = (t&3)*2 + (c>>3),
// qp = q ^ (sr&7)). Channels 12..15 are zero (buffer pre-zeroed).
// ---------------------------------------------------------------------------
__global__ __launch_bounds__(512) void fft_inv_packed(const float2* __restrict__ Xs,
                                                      const float* __restrict__ g,
                                                      const float2* __restrict__ tw,
                                                      unsigned short* __restrict__ modeBF)
{
    int rp = blockIdx.x;
    int kk = blockIdx.y;
    int b = rp / 6, c0 = (rp % 6) * 2;
    size_t rowa = (size_t)b * C_IN + c0;
    __shared__ float2 bufA[T_LEN];
    __shared__ float2 bufB[T_LEN];
    const float* gk = g + kk * NBINS;
    for (int f = threadIdx.x; f < T_LEN; f += 512) {
        int fe = (f <= 2048) ? f : (T_LEN - f);
        float2 A  = Xs[rowa * NBINS + fe];
        float2 Bv = Xs[(rowa + 1) * NBINS + fe];
        float gv = gk[fe];
        if (f > 2048) { A.y = -A.y; Bv.y = -Bv.y; }
        bufA[f] = make_float2(gv * (A.x - Bv.y), gv * (A.y + Bv.x));
    }
    __syncthreads();
    float2* z = fft_stages(bufA, bufB, tw, -1.f);
    const float invn = 1.f / (float)T_LEN;
    char* plane = (char*)modeBF + ((size_t)kk * B_SZ + b) * (T_LEN * 32);
    for (int t = threadIdx.x; t < T_LEN; t += 512) {
        unsigned int pk = (unsigned int)f2bf(z[t].x * invn) |
                          ((unsigned int)f2bf(z[t].y * invn) << 16);
        int q = ((t & 3) * 2 + (c0 >> 3)) ^ ((t >> 2) & 7);
        *(unsigned int*)(plane + (size_t)(t >> 2) * 128 + q * 16 + (c0 & 7) * 2) = pk;
    }
}

// ---------------------------------------------------------------------------
// conv1 via MFMA bf16 16x16x32: input mode plane [b][t][16c] (swizzled),
// K = 7d x 16c folded into 4 K=32 fragments (k = d_off*16 + c, zero-padded).
// Block = 128t x 32o; 4 waves x (32t x 32o); 16 MFMAs/wave.
// Output h1bf [b][t][32] (conv2's verified format).
// ---------------------------------------------------------------------------
__global__ __launch_bounds__(256) void conv1_mfma(
    const unsigned short* __restrict__ modeBF,   // this (k) base
    const unsigned short* __restrict__ Wp1,      // this k slot: 4096 ush
    const float* __restrict__ bias,
    const float* __restrict__ gamma,
    const float* __restrict__ beta,
    unsigned short* __restrict__ h1bf)
{
    __shared__ __align__(16) char smem[4352 + 8192 + 8192];
    char* Xl  = smem;              // 34 superrows * 128B (t0-4 .. t0+135 raw)
    char* Wl  = smem + 4352;       // 8192B
    char* rep = smem + 4352 + 8192;

    const int b = blockIdx.y;
    const int t0 = blockIdx.x * 128;
    const int tid = threadIdx.x;
    const char* plane = (const char*)modeBF + (size_t)b * (T_LEN * 32);
    const int sr0 = t0 >> 2;

    // stage X: 272 chunks; chunk (ls, qp) decodes t = sr_g*4 + ((qp^(sr_g&7))>>1)
    for (int i = tid; i < 272; i += 256) {
        int ls = i >> 3, qp = i & 7;
        int sr_g = sr0 - 1 + ls;
        int q = qp ^ (sr_g & 7);
        int t = sr_g * 4 + (q >> 1);
        float4 v = make_float4(0.f, 0.f, 0.f, 0.f);
        if (t >= 0 && t < T_LEN)
            v = *(const float4*)(plane + (size_t)sr_g * 128 + qp * 16);
        *(float4*)(Xl + (size_t)i * 16) = v;
    }
    for (int i = tid; i < 512; i += 256)
        ((float4*)Wl)[i] = ((const float4*)Wp1)[i];
    __syncthreads();

    const int w  = tid >> 6;
    const int l  = tid & 63;
    const int lo = l & 15;
    const int hi = l >> 4;

    short8v Bf[4][2];
#pragma unroll
    for (int dp = 0; dp < 4; ++dp)
#pragma unroll
        for (int n = 0; n < 2; ++n) {
            int o = n * 16 + lo;
            Bf[dp][n] = *(const short8v*)(Wl + dp * 2048 + o * 64 + hi * 16);
        }

    floatx4 acc[2][2];
#pragma unroll
    for (int m = 0; m < 2; ++m)
#pragma unroll
        for (int n = 0; n < 2; ++n)
            acc[m][n] = (floatx4){0.f, 0.f, 0.f, 0.f};

#pragma unroll
    for (int dp = 0; dp < 4; ++dp)
#pragma unroll
        for (int m = 0; m < 2; ++m) {
            int t_in = t0 + w * 32 + m * 16 + lo + dp * 2 + (hi >> 1) - 3;
            int sr_g = t_in >> 2;
            int ls = sr_g - sr0 + 1;
            int q = (t_in & 3) * 2 + (hi & 1);
            int qp = q ^ (sr_g & 7);
            short8v Af = *(const short8v*)(Xl + (size_t)ls * 128 + qp * 16);
#pragma unroll
            for (int n = 0; n < 2; ++n)
                acc[m][n] = __builtin_amdgcn_mfma_f32_16x16x32_bf16(
                    Af, Bf[dp][n], acc[m][n], 0, 0, 0);
        }

    // epilogue: BN + ReLU, scatter into h1bf superrow format, flat store
    const float rs = 1.f / sqrtf(1.f + 1e-5f);
#pragma unroll
    for (int n = 0; n < 2; ++n) {
        int o = n * 16 + lo;
        float sc = gamma[o] * rs;
        float bb = fmaf(bias[o], sc, beta[o]);
#pragma unroll
        for (int m = 0; m < 2; ++m)
#pragma unroll
            for (int r = 0; r < 4; ++r) {
                float v = fmaxf(fmaf(acc[m][n][r], sc, bb), 0.f);
                int t_loc = w * 32 + m * 16 + 4 * hi + r;
                int q = (t_loc & 1) * 4 + (o >> 3);
                int qp = q ^ ((t_loc >> 1) & 7);
                *(unsigned short*)(rep + (size_t)(t_loc >> 1) * 128 + qp * 16 +
                                   (o & 7) * 2) = f2bf(v);
            }
    }
    __syncthreads();
    char* dst = (char*)h1bf + (size_t)b * (T_LEN * 64) + (size_t)t0 * 64;
    for (int i = tid; i < 512; i += 256)
        ((float4*)dst)[i] = ((float4*)rep)[i];
}

// ---------------------------------------------------------------------------
// conv2 via MFMA bf16 (verified r12).
// ---------------------------------------------------------------------------
__global__ __launch_bounds__(256) void conv2_mfma(
    const unsigned short* __restrict__ h1bf,
    const unsigned short* __restrict__ Wp2,    // 5 planes of 4096B
    const float* __restrict__ bias,
    const float* __restrict__ gamma,
    const float* __restrict__ beta,
    unsigned short* __restrict__ h2bf)
{
    __shared__ __align__(16) char smem[9216 + 20480 + 16384];
    char* Xl  = smem;
    char* Wl  = smem + 9216;
    char* rep = smem + 9216 + 20480;

    const int b = blockIdx.y;
    const int t0 = blockIdx.x * 128;
    const int tid = threadIdx.x;
    const char* src = (const char*)h1bf + (size_t)b * (T_LEN * 64);

    for (int i = tid; i < 576; i += 256) {
        int sr_loc = i >> 3;
        int qp = i & 7;
        int key = (sr_loc + 4) & 7;
        int q = qp ^ key;
        int t = (t0 - 8) + sr_loc * 2 + (q >> 2);
        float4 v = make_float4(0.f, 0.f, 0.f, 0.f);
        if (t >= 0 && t < T_LEN)
            v = *(const float4*)(src + (ptrdiff_t)(t0 - 8) * 64 + (size_t)i * 16);
        *(float4*)(Xl + (size_t)i * 16) = v;
    }
    for (int i = tid; i < 1280; i += 256)
        *(float4*)(Wl + (size_t)i * 16) = *(const float4*)((const char*)Wp2 + (size_t)i * 16);
    __syncthreads();

    const int w  = tid >> 6;
    const int l  = tid & 63;
    const int lo = l & 15;
    const int hi = l >> 4;

    short8v Bf[5][4];
#pragma unroll
    for (int d = 0; d < 5; ++d)
#pragma unroll
        for (int n = 0; n < 4; ++n) {
            int o = n * 16 + lo;
            int sr = o >> 1;
            int q = (o & 1) * 4 + hi;
            int qp = q ^ (sr & 7);
            Bf[d][n] = *(const short8v*)(Wl + (size_t)d * 4096 + sr * 128 + qp * 16);
        }

    floatx4 acc[2][4];
#pragma unroll
    for (int m = 0; m < 2; ++m)
#pragma unroll
        for (int n = 0; n < 4; ++n)
            acc[m][n] = (floatx4){0.f, 0.f, 0.f, 0.f};

#pragma unroll
    for (int d = 0; d < 5; ++d)
#pragma unroll
        for (int m = 0; m < 2; ++m) {
            int tl = w * 32 + m * 16 + lo + d + 6;
            int sr = tl >> 1;
            int q = (tl & 1) * 4 + hi;
            int qp = q ^ ((sr + 4) & 7);
            short8v Af = *(const short8v*)(Xl + (size_t)sr * 128 + qp * 16);
#pragma unroll
            for (int n = 0; n < 4; ++n)
                acc[m][n] = __builtin_amdgcn_mfma_f32_16x16x32_bf16(
                    Af, Bf[d][n], acc[m][n], 0, 0, 0);
        }

    const float rs = 1.f / sqrtf(1.f + 1e-5f);
#pragma unroll
    for (int n = 0; n < 4; ++n) {
        int o = n * 16 + lo;
        float sc = gamma[o] * rs;
        float bb = fmaf(bias[o], sc, beta[o]);
        int cq = o >> 3;
#pragma unroll
        for (int m = 0; m < 2; ++m)
#pragma unroll
            for (int r = 0; r < 4; ++r) {
                float v = fmaxf(fmaf(acc[m][n][r], sc, bb), 0.f);
                int trow = w * 32 + m * 16 + 4 * hi + r;
                *(unsigned short*)(rep + (size_t)trow * 128 +
                                   ((cq ^ (trow & 7)) * 16) + (o & 7) * 2) = f2bf(v);
            }
    }
    __syncthreads();
    char* dst = (char*)h2bf + (size_t)b * (T_LEN * 128) + (size_t)t0 * 128;
    for (int i = tid; i < 1024; i += 256)
        *(float4*)(dst + (size_t)i * 16) = *(float4*)(rep + (size_t)i * 16);
}

// ---------------------------------------------------------------------------
// conv3 via MFMA bf16 (verified r11): fused BN+ReLU+mean -> feats atomicAdd.
// ---------------------------------------------------------------------------
__global__ __launch_bounds__(256) void conv3_mfma(
    const unsigned short* __restrict__ h2bf,
    const unsigned short* __restrict__ Wp,
    const float* __restrict__ bias,
    const float* __restrict__ gamma,
    const float* __restrict__ beta,
    float* __restrict__ feats,
    int k_slot)
{
    __shared__ __align__(16) char smem[16640 + 24576];
    char* Xl = smem;
    char* Wl = smem + 16640;

    const int b = blockIdx.y;
    const int t0 = blockIdx.x * 128;
    const int tid = threadIdx.x;

    for (int i = tid; i < 1040; i += 256) {
        int row = i >> 3;
        int tg = t0 - 1 + row;
        float4 v = make_float4(0.f, 0.f, 0.f, 0.f);
        if (tg >= 0 && tg < T_LEN)
            v = *(const float4*)((const char*)h2bf + ((size_t)b * T_LEN + tg) * 128 + (i & 7) * 16);
        *(float4*)(Xl + (size_t)i * 16) = v;
    }
    for (int i = tid; i < 1536; i += 256)
        *(float4*)(Wl + (size_t)i * 16) = *(const float4*)((const char*)Wp + (size_t)i * 16);
    __syncthreads();

    const int w  = tid >> 6;
    const int l  = tid & 63;
    const int lo = l & 15;
    const int hi = l >> 4;

    short8v Bf[6][4];
#pragma unroll
    for (int d = 0; d < 3; ++d)
#pragma unroll
        for (int ch = 0; ch < 2; ++ch)
#pragma unroll
            for (int n = 0; n < 4; ++n) {
                int o = n * 16 + lo;
                int blk = (4 * ch + hi) ^ (o & 7);
                Bf[d * 2 + ch][n] =
                    *(const short8v*)(Wl + (size_t)(d * 64 + o) * 128 + blk * 16);
            }

    floatx4 acc[2][4];
#pragma unroll
    for (int m = 0; m < 2; ++m)
#pragma unroll
        for (int n = 0; n < 4; ++n)
            acc[m][n] = (floatx4){0.f, 0.f, 0.f, 0.f};

#pragma unroll
    for (int d = 0; d < 3; ++d)
#pragma unroll
        for (int ch = 0; ch < 2; ++ch) {
#pragma unroll
            for (int m = 0; m < 2; ++m) {
                int tl = w * 32 + m * 16 + lo + d;
                int blk = (4 * ch + hi) ^ ((tl - 1) & 7);
                short8v Af = *(const short8v*)(Xl + (size_t)tl * 128 + blk * 16);
#pragma unroll
                for (int n = 0; n < 4; ++n)
                    acc[m][n] = __builtin_amdgcn_mfma_f32_16x16x32_bf16(
                        Af, Bf[d * 2 + ch][n], acc[m][n], 0, 0, 0);
            }
        }

    const float rs = 1.f / sqrtf(1.f + 1e-5f);
#pragma unroll
    for (int n = 0; n < 4; ++n) {
        int o = n * 16 + lo;
        float sc = gamma[o] * rs;
        float bb = fmaf(bias[o], sc, beta[o]);
        float s = 0.f;
#pragma unroll
        for (int m = 0; m < 2; ++m)
#pragma unroll
            for (int r = 0; r < 4; ++r)
                s += fmaxf(fmaf(acc[m][n][r], sc, bb), 0.f);
        s += __shfl_xor(s, 16, 64);
        s += __shfl_xor(s, 32, 64);
        if (hi == 0)
            atomicAdd(&feats[b * (KM * FEAT) + k_slot * FEAT + o], s * (1.f / (float)T_LEN));
    }
}

// ---------------------------------------------------------------------------
// Classifier
// ---------------------------------------------------------------------------
__global__ __launch_bounds__(128) void classifier_kernel(const float* __restrict__ feats,
                                                         const float* __restrict__ Wc1,
                                                         const float* __restrict__ bc1,
                                                         const float* __restrict__ Wc2,
                                                         const float* __restrict__ bc2,
                                                         float* __restrict__ out)
{
    int b = blockIdx.x;
    int j = threadIdx.x;
    __shared__ float h[128];
    float acc = bc1[j];
    const float* fb = feats + b * 256;
    for (int i = 0; i < 256; ++i) acc = fmaf(fb[i], Wc1[j * 256 + i], acc);
    h[j] = fmaxf(acc, 0.f);
    __syncthreads();
    if (j < 10) {
        float acc2 = bc2[j];
        for (int i = 0; i < 128; ++i) acc2 = fmaf(h[i], Wc2[j * 128 + i], acc2);
        out[b * 10 + j] = acc2;
    }
}

extern "C" void kernel_launch(void* const* d_in, const int* in_sizes, int n_in,
                              void* d_out, int out_size, void* d_ws, size_t ws_size,
                              hipStream_t stream)
{
    const float* x     = (const float*)d_in[0];
    const float* alpha = (const float*)d_in[1];
    const float* tau   = (const float*)d_in[2];
    const float* omega = (const float*)d_in[3];
    const float* W1    = (const float*)d_in[4];
    const float* b1    = (const float*)d_in[5];
    const float* g1    = (const float*)d_in[6];
    const float* be1   = (const float*)d_in[7];
    const float* W2    = (const float*)d_in[8];
    const float* b2    = (const float*)d_in[9];
    const float* g2    = (const float*)d_in[10];
    const float* be2   = (const float*)d_in[11];
    const float* W3    = (const float*)d_in[12];
    const float* b3    = (const float*)d_in[13];
    const float* g3    = (const float*)d_in[14];
    const float* be3   = (const float*)d_in[15];
    const float* Wc1   = (const float*)d_in[16];
    const float* bc1   = (const float*)d_in[17];
    const float* Wc2   = (const float*)d_in[18];
    const float* bc2   = (const float*)d_in[19];

    const int NROWS = B_SZ * C_IN;   // 768
    float* ws = (float*)d_ws;
    float2* tw   = (float2*)ws;                                  // 4096 floats
    float* g     = ws + 4096;                                    // 8196 floats
    float2* Xs   = (float2*)(ws + 4096 + 4 * NBINS);             // 3,147,264 floats
    unsigned short* modeBF = (unsigned short*)(ws + 4096 + 4 * NBINS + (size_t)NROWS * NBINS * 2);
    // modeBF: 4k * 64b * 4096t * 16c ush = 16,777,216 ush (33.5 MB)
    unsigned short* h1bf = modeBF + (size_t)KM * B_SZ * T_LEN * 16;
    unsigned short* h2bf = h1bf + (size_t)B_SZ * T_LEN * 32;
    float* feats = (float*)(h2bf + (size_t)B_SZ * T_LEN * 64);
    unsigned short* Wp1 = (unsigned short*)(feats + B_SZ * KM * FEAT);   // 16384 ush
    unsigned short* Wp2 = Wp1 + KM * 4096;                               // 40960 ush
    unsigned short* Wp3 = Wp2 + KM * 5 * 2048;                           // 49152 ush

    gains_kernel<<<(NBINS + 255) / 256, 256, 0, stream>>>(alpha, tau, omega, g);
    twiddle_kernel<<<8, 256, 0, stream>>>(tw);
    zero_kernel<<<64, 256, 0, stream>>>(feats, B_SZ * KM * FEAT);
    zero4_kernel<<<8192, 256, 0, stream>>>((float4*)modeBF, KM * B_SZ * T_LEN * 32 / 16);
    prep_w1<<<(KM * 4 * 32 * 32 + 255) / 256, 256, 0, stream>>>(W1, Wp1);
    prep_w2<<<(KM * 5 * 64 * 32 + 255) / 256, 256, 0, stream>>>(W2, Wp2);
    prep_w3<<<(KM * 3 * 64 * 64 + 255) / 256, 256, 0, stream>>>(W3, Wp3);
    fft_fwd_packed<<<NROWS / 2, 512, 0, stream>>>(x, tw, Xs);

    // all 4 modes in one k-batched inverse-FFT dispatch
    fft_inv_packed<<<dim3(NROWS / 2, KM), 512, 0, stream>>>(Xs, g, tw, modeBF);

    for (int k = 0; k < KM; ++k) {
        conv1_mfma<<<dim3(T_LEN / 128, B_SZ), 256, 0, stream>>>(
            modeBF + (size_t)k * B_SZ * T_LEN * 16, Wp1 + (size_t)k * 4096,
            b1 + k * 32, g1 + k * 32, be1 + k * 32, h1bf);
        conv2_mfma<<<dim3(T_LEN / 128, B_SZ), 256, 0, stream>>>(
            h1bf, Wp2 + (size_t)k * 5 * 2048, b2 + k * 64, g2 + k * 64, be2 + k * 64, h2bf);
        conv3_mfma<<<dim3(T_LEN / 128, B_SZ), 256, 0, stream>>>(
            h2bf, Wp3 + (size_t)k * 3 * 64 * 64, b3 + k * 64, g3 + k * 64, be3 + k * 64,
            feats, k);
    }

    classifier_kernel<<<B_SZ, 128, 0, stream>>>(feats, Wc1, bc1, Wc2, bc2, (float*)d_out);
}

// Round 15
// 303.973 us; speedup vs baseline: 3.5657x; 1.0969x over previous
//
#include <hip/hip_runtime.h>
#include <math.h>

#define T_LEN 4096
#define NBINS 2049          // T/2+1
#define B_SZ 64
#define C_IN 12
#define KM 4
#define FEAT 64

typedef __attribute__((ext_vector_type(8))) short short8v;   // 8 bf16 (4 VGPRs)
typedef __attribute__((ext_vector_type(4))) float floatx4;

// fp32 -> bf16 with RNE
__device__ __forceinline__ unsigned short f2bf(float f)
{
    unsigned int u = __float_as_uint(f);
    u += 0x7FFFu + ((u >> 16) & 1u);
    return (unsigned short)(u >> 16);
}

// ---------------------------------------------------------------------------
// Gains: UVMD Gauss-Seidel is linear in X with real freq-only coefficients.
// ---------------------------------------------------------------------------
__global__ void gains_kernel(const float* __restrict__ alpha,
                             const float* __restrict__ tau,
                             const float* __restrict__ omega,
                             float* __restrict__ g)
{
    int f = blockIdx.x * 256 + threadIdx.x;
    if (f >= NBINS) return;
    float freq = 0.5f * (float)f / 2048.0f;
    float a[4] = {0.f, 0.f, 0.f, 0.f};
    float s = 0.f, lamc = 0.f;
    for (int l = 0; l < 8; ++l) {
        for (int k = 0; k < 4; ++k) {
            float r = 1.f - (s - a[k]) + 0.5f * lamc;
            float d = freq - omega[k];
            float denom = 1.f + alpha[l * 4 + k] * d * d;
            float anew = r / denom;
            s += anew - a[k];
            a[k] = anew;
        }
        lamc += tau[l] * (1.f - s);
    }
    for (int k = 0; k < 4; ++k) g[k * NBINS + f] = a[k];
}

__global__ void twiddle_kernel(float2* __restrict__ tw)
{
    int i = blockIdx.x * 256 + threadIdx.x;
    if (i < 2048) {
        float ang = -(float)M_PI * (float)i / 2048.0f;
        float sn, cs;
        sincosf(ang, &sn, &cs);
        tw[i] = make_float2(cs, sn);
    }
}

__global__ void zero_kernel(float* __restrict__ p, int n)
{
    int i = blockIdx.x * 256 + threadIdx.x;
    if (i < n) p[i] = 0.f;
}

// ---------------------------------------------------------------------------
// Weight prep conv1 (verified r13): Wp1[k][dpair][o][kidx] bf16.
// ---------------------------------------------------------------------------
__global__ void prep_w1(const float* __restrict__ W1, unsigned short* __restrict__ Wp1)
{
    int i = blockIdx.x * 256 + threadIdx.x;
    if (i >= KM * 4 * 32 * 32) return;      // 16384
    int kidx  = i & 31;
    int o     = (i >> 5) & 31;
    int dpair = (i >> 10) & 3;
    int k     = i >> 12;
    int d = dpair * 2 + (kidx >> 4);
    int c = kidx & 15;
    float v = (d < 7 && c < 12) ? W1[(((size_t)k * 32 + o) * 12 + c) * 7 + d] : 0.f;
    Wp1[(size_t)k * 4096 + dpair * 1024 + o * 32 + kidx] = f2bf(v);
}

// ---------------------------------------------------------------------------
// Weight prep conv2 (verified r12): superrow = 2 o-rows = 128B.
// ---------------------------------------------------------------------------
__global__ void prep_w2(const float* __restrict__ W2, unsigned short* __restrict__ Wp2)
{
    int i = blockIdx.x * 256 + threadIdx.x;
    if (i >= KM * 5 * 64 * 32) return;
    int c = i & 31;
    int o = (i >> 5) & 63;
    int kd = i >> 11;
    int d = kd % 5, k = kd / 5;
    float v = W2[(((size_t)k * 64 + o) * 32 + c) * 5 + d];
    int sr = o >> 1;
    int q = (o & 1) * 4 + (c >> 3);
    int qp = q ^ (sr & 7);
    Wp2[(size_t)(k * 5 + d) * 2048 + sr * 64 + qp * 8 + (c & 7)] = f2bf(v);
}

// ---------------------------------------------------------------------------
// Weight prep conv3 (verified r11).
// ---------------------------------------------------------------------------
__global__ void prep_w3(const float* __restrict__ W3, unsigned short* __restrict__ Wp)
{
    int i = blockIdx.x * 256 + threadIdx.x;
    if (i >= KM * 3 * 64 * 64) return;
    int c = i & 63;
    int o = (i >> 6) & 63;
    int kd = i >> 12;
    int d = kd % 3, k = kd / 3;
    float v = W3[(((size_t)k * 64 + o) * 64 + c) * 3 + d];
    int blk = (c >> 3) ^ (o & 7);
    Wp[(size_t)k * (3 * 64 * 64) + (d * 64 + o) * 64 + blk * 8 + (c & 7)] = f2bf(v);
}

// ---------------------------------------------------------------------------
// Stockham radix-2 stages; twiddles from LUT. syf=+1 fwd, -1 inv.
// ---------------------------------------------------------------------------
__device__ inline float2* fft_stages(float2* bufA, float2* bufB,
                                     const float2* __restrict__ tw, float syf)
{
    float2* src = bufA;
    float2* dst = bufB;
    for (int s = 0; s < 12; ++s) {
        int m = 1 << s;
        for (int p = threadIdx.x; p < 2048; p += 512) {
            int j = p >> s;
            int jm = j << s;
            float2 c0 = src[p];
            float2 c1 = src[p + 2048];
            float2 w = tw[jm & 2047];
            float cs = w.x, sn = syf * w.y;
            float2 d0 = make_float2(c0.x + c1.x, c0.y + c1.y);
            float2 t1 = make_float2(c0.x - c1.x, c0.y - c1.y);
            float2 d1 = make_float2(cs * t1.x - sn * t1.y, cs * t1.y + sn * t1.x);
            dst[jm + p] = d0;
            dst[jm + p + m] = d1;
        }
        __syncthreads();
        float2* tmp = src; src = dst; dst = tmp;
    }
    return src;
}

__global__ __launch_bounds__(512) void fft_fwd_packed(const float* __restrict__ x,
                                                      const float2* __restrict__ tw,
                                                      float2* __restrict__ Xs)
{
    int rp = blockIdx.x;
    int b = rp / 6, c0 = (rp % 6) * 2;
    __shared__ float2 bufA[T_LEN];
    __shared__ float2 bufB[T_LEN];
    for (int t = threadIdx.x; t < T_LEN; t += 512) {
        const float* px = x + ((size_t)b * T_LEN + t) * C_IN + c0;
        bufA[t] = make_float2(px[0], px[1]);
    }
    __syncthreads();
    float2* Z = fft_stages(bufA, bufB, tw, 1.f);
    size_t row = (size_t)b * C_IN + c0;
    for (int f = threadIdx.x; f <= 2048; f += 512) {
        float2 z  = Z[f];
        float2 zm = Z[(T_LEN - f) & (T_LEN - 1)];
        Xs[row * NBINS + f]       = make_float2(0.5f * (z.x + zm.x), 0.5f * (z.y - zm.y));
        Xs[(row + 1) * NBINS + f] = make_float2(0.5f * (z.y + zm.y), 0.5f * (zm.x - z.x));
    }
}

// ---------------------------------------------------------------------------
// Inverse FFT, k-batched (blockIdx.y = k). Output: contiguous bf16-pair
// planes mode[k][b][pair][t] (uint per t) -- fully coalesced full-line
// writes, each line written exactly once by one block (fixes the r13
// 172 MB write amplification).
// ---------------------------------------------------------------------------
__global__ __launch_bounds__(512) void fft_inv_packed(const float2* __restrict__ Xs,
                                                      const float* __restrict__ g,
                                                      const float2* __restrict__ tw,
                                                      unsigned int* __restrict__ modeU)
{
    int rp = blockIdx.x;
    int kk = blockIdx.y;
    int b = rp / 6, pr = rp % 6;
    int c0 = pr * 2;
    size_t rowa = (size_t)b * C_IN + c0;
    __shared__ float2 bufA[T_LEN];
    __shared__ float2 bufB[T_LEN];
    const float* gk = g + kk * NBINS;
    for (int f = threadIdx.x; f < T_LEN; f += 512) {
        int fe = (f <= 2048) ? f : (T_LEN - f);
        float2 A  = Xs[rowa * NBINS + fe];
        float2 Bv = Xs[(rowa + 1) * NBINS + fe];
        float gv = gk[fe];
        if (f > 2048) { A.y = -A.y; Bv.y = -Bv.y; }
        bufA[f] = make_float2(gv * (A.x - Bv.y), gv * (A.y + Bv.x));
    }
    __syncthreads();
    float2* z = fft_stages(bufA, bufB, tw, -1.f);
    const float invn = 1.f / (float)T_LEN;
    unsigned int* plane = modeU + (((size_t)kk * B_SZ + b) * 6 + pr) * T_LEN;
    for (int t = threadIdx.x; t < T_LEN; t += 512) {
        unsigned int pk = (unsigned int)f2bf(z[t].x * invn) |
                          ((unsigned int)f2bf(z[t].y * invn) << 16);
        plane[t] = pk;
    }
}

// ---------------------------------------------------------------------------
// conv1 via MFMA bf16 16x16x32 (MFMA body verified r13). Staging rebuilds
// the swizzled Xl tile from 6 contiguous pair planes: per (pair, 4-t chunk)
// one coalesced 16B read, then 4x 4B ds-scatter. Pairs 6,7 synthesize zeros.
// ---------------------------------------------------------------------------
__global__ __launch_bounds__(256) void conv1_mfma(
    const unsigned int* __restrict__ pairsK,     // this k: [b][pair][t] uints
    const unsigned short* __restrict__ Wp1,      // this k slot: 4096 ush
    const float* __restrict__ bias,
    const float* __restrict__ gamma,
    const float* __restrict__ beta,
    unsigned short* __restrict__ h1bf)
{
    __shared__ __align__(16) char smem[4352 + 8192 + 8192];
    char* Xl  = smem;              // 34 superrows * 128B, t in [t0-4, t0+132)
    char* Wl  = smem + 4352;       // 8192B
    char* rep = smem + 4352 + 8192;

    const int b = blockIdx.y;
    const int t0 = blockIdx.x * 128;
    const int tid = threadIdx.x;
    const unsigned int* planes = pairsK + (size_t)b * 6 * T_LEN;
    const int sr0 = t0 >> 2;

    // stage X: 8 pair-slots x 34 4-t chunks
    for (int i = tid; i < 272; i += 256) {
        int p = i / 34;            // pair slot 0..7 (6,7 = zero channels)
        int tc = i % 34;
        int t_base = t0 - 4 + tc * 4;
        unsigned int vv[4] = {0u, 0u, 0u, 0u};
        if (p < 6) {
            const unsigned int* pl = planes + (size_t)p * T_LEN;
            if (t_base >= 0 && t_base + 3 < T_LEN) {
                uint4 v4 = *(const uint4*)(pl + t_base);
                vv[0] = v4.x; vv[1] = v4.y; vv[2] = v4.z; vv[3] = v4.w;
            } else {
#pragma unroll
                for (int e = 0; e < 4; ++e) {
                    int t = t_base + e;
                    vv[e] = (t >= 0 && t < T_LEN) ? pl[t] : 0u;
                }
            }
        }
        int cb = p >> 2, j = p & 3;
        int sr_g = t_base >> 2;            // all 4 elems share the superrow
        int ls = sr_g - sr0 + 1;           // 0..33
        int key = sr_g & 7;
#pragma unroll
        for (int e = 0; e < 4; ++e) {
            int q = e * 2 + cb;            // t&3 == e
            int qp = q ^ key;
            *(unsigned int*)(Xl + (size_t)ls * 128 + qp * 16 + j * 4) = vv[e];
        }
    }
    for (int i = tid; i < 512; i += 256)
        ((float4*)Wl)[i] = ((const float4*)Wp1)[i];
    __syncthreads();

    const int w  = tid >> 6;
    const int l  = tid & 63;
    const int lo = l & 15;
    const int hi = l >> 4;

    short8v Bf[4][2];
#pragma unroll
    for (int dp = 0; dp < 4; ++dp)
#pragma unroll
        for (int n = 0; n < 2; ++n) {
            int o = n * 16 + lo;
            Bf[dp][n] = *(const short8v*)(Wl + dp * 2048 + o * 64 + hi * 16);
        }

    floatx4 acc[2][2];
#pragma unroll
    for (int m = 0; m < 2; ++m)
#pragma unroll
        for (int n = 0; n < 2; ++n)
            acc[m][n] = (floatx4){0.f, 0.f, 0.f, 0.f};

#pragma unroll
    for (int dp = 0; dp < 4; ++dp)
#pragma unroll
        for (int m = 0; m < 2; ++m) {
            int t_in = t0 + w * 32 + m * 16 + lo + dp * 2 + (hi >> 1) - 3;
            int sr_g = t_in >> 2;
            int ls = sr_g - sr0 + 1;
            int q = (t_in & 3) * 2 + (hi & 1);
            int qp = q ^ (sr_g & 7);
            short8v Af = *(const short8v*)(Xl + (size_t)ls * 128 + qp * 16);
#pragma unroll
            for (int n = 0; n < 2; ++n)
                acc[m][n] = __builtin_amdgcn_mfma_f32_16x16x32_bf16(
                    Af, Bf[dp][n], acc[m][n], 0, 0, 0);
        }

    // epilogue: BN + ReLU, scatter into h1bf superrow format, flat store
    const float rs = 1.f / sqrtf(1.f + 1e-5f);
#pragma unroll
    for (int n = 0; n < 2; ++n) {
        int o = n * 16 + lo;
        float sc = gamma[o] * rs;
        float bb = fmaf(bias[o], sc, beta[o]);
#pragma unroll
        for (int m = 0; m < 2; ++m)
#pragma unroll
            for (int r = 0; r < 4; ++r) {
                float v = fmaxf(fmaf(acc[m][n][r], sc, bb), 0.f);
                int t_loc = w * 32 + m * 16 + 4 * hi + r;
                int q = (t_loc & 1) * 4 + (o >> 3);
                int qp = q ^ ((t_loc >> 1) & 7);
                *(unsigned short*)(rep + (size_t)(t_loc >> 1) * 128 + qp * 16 +
                                   (o & 7) * 2) = f2bf(v);
            }
    }
    __syncthreads();
    char* dst = (char*)h1bf + (size_t)b * (T_LEN * 64) + (size_t)t0 * 64;
    for (int i = tid; i < 512; i += 256)
        ((float4*)dst)[i] = ((float4*)rep)[i];
}

// ---------------------------------------------------------------------------
// conv2 via MFMA bf16 (verified r12).
// ---------------------------------------------------------------------------
__global__ __launch_bounds__(256) void conv2_mfma(
    const unsigned short* __restrict__ h1bf,
    const unsigned short* __restrict__ Wp2,    // 5 planes of 4096B
    const float* __restrict__ bias,
    const float* __restrict__ gamma,
    const float* __restrict__ beta,
    unsigned short* __restrict__ h2bf)
{
    __shared__ __align__(16) char smem[9216 + 20480 + 16384];
    char* Xl  = smem;
    char* Wl  = smem + 9216;
    char* rep = smem + 9216 + 20480;

    const int b = blockIdx.y;
    const int t0 = blockIdx.x * 128;
    const int tid = threadIdx.x;
    const char* src = (const char*)h1bf + (size_t)b * (T_LEN * 64);

    for (int i = tid; i < 576; i += 256) {
        int sr_loc = i >> 3;
        int qp = i & 7;
        int key = (sr_loc + 4) & 7;
        int q = qp ^ key;
        int t = (t0 - 8) + sr_loc * 2 + (q >> 2);
        float4 v = make_float4(0.f, 0.f, 0.f, 0.f);
        if (t >= 0 && t < T_LEN)
            v = *(const float4*)(src + (ptrdiff_t)(t0 - 8) * 64 + (size_t)i * 16);
        *(float4*)(Xl + (size_t)i * 16) = v;
    }
    for (int i = tid; i < 1280; i += 256)
        *(float4*)(Wl + (size_t)i * 16) = *(const float4*)((const char*)Wp2 + (size_t)i * 16);
    __syncthreads();

    const int w  = tid >> 6;
    const int l  = tid & 63;
    const int lo = l & 15;
    const int hi = l >> 4;

    short8v Bf[5][4];
#pragma unroll
    for (int d = 0; d < 5; ++d)
#pragma unroll
        for (int n = 0; n < 4; ++n) {
            int o = n * 16 + lo;
            int sr = o >> 1;
            int q = (o & 1) * 4 + hi;
            int qp = q ^ (sr & 7);
            Bf[d][n] = *(const short8v*)(Wl + (size_t)d * 4096 + sr * 128 + qp * 16);
        }

    floatx4 acc[2][4];
#pragma unroll
    for (int m = 0; m < 2; ++m)
#pragma unroll
        for (int n = 0; n < 4; ++n)
            acc[m][n] = (floatx4){0.f, 0.f, 0.f, 0.f};

#pragma unroll
    for (int d = 0; d < 5; ++d)
#pragma unroll
        for (int m = 0; m < 2; ++m) {
            int tl = w * 32 + m * 16 + lo + d + 6;
            int sr = tl >> 1;
            int q = (tl & 1) * 4 + hi;
            int qp = q ^ ((sr + 4) & 7);
            short8v Af = *(const short8v*)(Xl + (size_t)sr * 128 + qp * 16);
#pragma unroll
            for (int n = 0; n < 4; ++n)
                acc[m][n] = __builtin_amdgcn_mfma_f32_16x16x32_bf16(
                    Af, Bf[d][n], acc[m][n], 0, 0, 0);
        }

    const float rs = 1.f / sqrtf(1.f + 1e-5f);
#pragma unroll
    for (int n = 0; n < 4; ++n) {
        int o = n * 16 + lo;
        float sc = gamma[o] * rs;
        float bb = fmaf(bias[o], sc, beta[o]);
        int cq = o >> 3;
#pragma unroll
        for (int m = 0; m < 2; ++m)
#pragma unroll
            for (int r = 0; r < 4; ++r) {
                float v = fmaxf(fmaf(acc[m][n][r], sc, bb), 0.f);
                int trow = w * 32 + m * 16 + 4 * hi + r;
                *(unsigned short*)(rep + (size_t)trow * 128 +
                                   ((cq ^ (trow & 7)) * 16) + (o & 7) * 2) = f2bf(v);
            }
    }
    __syncthreads();
    char* dst = (char*)h2bf + (size_t)b * (T_LEN * 128) + (size_t)t0 * 128;
    for (int i = tid; i < 1024; i += 256)
        *(float4*)(dst + (size_t)i * 16) = *(float4*)(rep + (size_t)i * 16);
}

// ---------------------------------------------------------------------------
// conv3 via MFMA bf16 (verified r11): fused BN+ReLU+mean -> feats atomicAdd.
// ---------------------------------------------------------------------------
__global__ __launch_bounds__(256) void conv3_mfma(
    const unsigned short* __restrict__ h2bf,
    const unsigned short* __restrict__ Wp,
    const float* __restrict__ bias,
    const float* __restrict__ gamma,
    const float* __restrict__ beta,
    float* __restrict__ feats,
    int k_slot)
{
    __shared__ __align__(16) char smem[16640 + 24576];
    char* Xl = smem;
    char* Wl = smem + 16640;

    const int b = blockIdx.y;
    const int t0 = blockIdx.x * 128;
    const int tid = threadIdx.x;

    for (int i = tid; i < 1040; i += 256) {
        int row = i >> 3;
        int tg = t0 - 1 + row;
        float4 v = make_float4(0.f, 0.f, 0.f, 0.f);
        if (tg >= 0 && tg < T_LEN)
            v = *(const float4*)((const char*)h2bf + ((size_t)b * T_LEN + tg) * 128 + (i & 7) * 16);
        *(float4*)(Xl + (size_t)i * 16) = v;
    }
    for (int i = tid; i < 1536; i += 256)
        *(float4*)(Wl + (size_t)i * 16) = *(const float4*)((const char*)Wp + (size_t)i * 16);
    __syncthreads();

    const int w  = tid >> 6;
    const int l  = tid & 63;
    const int lo = l & 15;
    const int hi = l >> 4;

    short8v Bf[6][4];
#pragma unroll
    for (int d = 0; d < 3; ++d)
#pragma unroll
        for (int ch = 0; ch < 2; ++ch)
#pragma unroll
            for (int n = 0; n < 4; ++n) {
                int o = n * 16 + lo;
                int blk = (4 * ch + hi) ^ (o & 7);
                Bf[d * 2 + ch][n] =
                    *(const short8v*)(Wl + (size_t)(d * 64 + o) * 128 + blk * 16);
            }

    floatx4 acc[2][4];
#pragma unroll
    for (int m = 0; m < 2; ++m)
#pragma unroll
        for (int n = 0; n < 4; ++n)
            acc[m][n] = (floatx4){0.f, 0.f, 0.f, 0.f};

#pragma unroll
    for (int d = 0; d < 3; ++d)
#pragma unroll
        for (int ch = 0; ch < 2; ++ch) {
#pragma unroll
            for (int m = 0; m < 2; ++m) {
                int tl = w * 32 + m * 16 + lo + d;
                int blk = (4 * ch + hi) ^ ((tl - 1) & 7);
                short8v Af = *(const short8v*)(Xl + (size_t)tl * 128 + blk * 16);
#pragma unroll
                for (int n = 0; n < 4; ++n)
                    acc[m][n] = __builtin_amdgcn_mfma_f32_16x16x32_bf16(
                        Af, Bf[d * 2 + ch][n], acc[m][n], 0, 0, 0);
            }
        }

    const float rs = 1.f / sqrtf(1.f + 1e-5f);
#pragma unroll
    for (int n = 0; n < 4; ++n) {
        int o = n * 16 + lo;
        float sc = gamma[o] * rs;
        float bb = fmaf(bias[o], sc, beta[o]);
        float s = 0.f;
#pragma unroll
        for (int m = 0; m < 2; ++m)
#pragma unroll
            for (int r = 0; r < 4; ++r)
                s += fmaxf(fmaf(acc[m][n][r], sc, bb), 0.f);
        s += __shfl_xor(s, 16, 64);
        s += __shfl_xor(s, 32, 64);
        if (hi == 0)
            atomicAdd(&feats[b * (KM * FEAT) + k_slot * FEAT + o], s * (1.f / (float)T_LEN));
    }
}

// ---------------------------------------------------------------------------
// Classifier
// ---------------------------------------------------------------------------
__global__ __launch_bounds__(128) void classifier_kernel(const float* __restrict__ feats,
                                                         const float* __restrict__ Wc1,
                                                         const float* __restrict__ bc1,
                                                         const float* __restrict__ Wc2,
                                                         const float* __restrict__ bc2,
                                                         float* __restrict__ out)
{
    int b = blockIdx.x;
    int j = threadIdx.x;
    __shared__ float h[128];
    float acc = bc1[j];
    const float* fb = feats + b * 256;
    for (int i = 0; i < 256; ++i) acc = fmaf(fb[i], Wc1[j * 256 + i], acc);
    h[j] = fmaxf(acc, 0.f);
    __syncthreads();
    if (j < 10) {
        float acc2 = bc2[j];
        for (int i = 0; i < 128; ++i) acc2 = fmaf(h[i], Wc2[j * 128 + i], acc2);
        out[b * 10 + j] = acc2;
    }
}

extern "C" void kernel_launch(void* const* d_in, const int* in_sizes, int n_in,
                              void* d_out, int out_size, void* d_ws, size_t ws_size,
                              hipStream_t stream)
{
    const float* x     = (const float*)d_in[0];
    const float* alpha = (const float*)d_in[1];
    const float* tau   = (const float*)d_in[2];
    const float* omega = (const float*)d_in[3];
    const float* W1    = (const float*)d_in[4];
    const float* b1    = (const float*)d_in[5];
    const float* g1    = (const float*)d_in[6];
    const float* be1   = (const float*)d_in[7];
    const float* W2    = (const float*)d_in[8];
    const float* b2    = (const float*)d_in[9];
    const float* g2    = (const float*)d_in[10];
    const float* be2   = (const float*)d_in[11];
    const float* W3    = (const float*)d_in[12];
    const float* b3    = (const float*)d_in[13];
    const float* g3    = (const float*)d_in[14];
    const float* be3   = (const float*)d_in[15];
    const float* Wc1   = (const float*)d_in[16];
    const float* bc1   = (const float*)d_in[17];
    const float* Wc2   = (const float*)d_in[18];
    const float* bc2   = (const float*)d_in[19];

    const int NROWS = B_SZ * C_IN;   // 768
    float* ws = (float*)d_ws;
    float2* tw   = (float2*)ws;                                  // 4096 floats
    float* g     = ws + 4096;                                    // 8196 floats
    float2* Xs   = (float2*)(ws + 4096 + 4 * NBINS);             // 3,147,264 floats
    unsigned int* modeU = (unsigned int*)(ws + 4096 + 4 * NBINS + (size_t)NROWS * NBINS * 2);
    // modeU: 4k * 64b * 6pair * 4096t uints = 25.2 MB
    unsigned short* h1bf = (unsigned short*)(modeU + (size_t)KM * B_SZ * 6 * T_LEN);
    unsigned short* h2bf = h1bf + (size_t)B_SZ * T_LEN * 32;
    float* feats = (float*)(h2bf + (size_t)B_SZ * T_LEN * 64);
    unsigned short* Wp1 = (unsigned short*)(feats + B_SZ * KM * FEAT);   // 16384 ush
    unsigned short* Wp2 = Wp1 + KM * 4096;                               // 40960 ush
    unsigned short* Wp3 = Wp2 + KM * 5 * 2048;                           // 49152 ush

    gains_kernel<<<(NBINS + 255) / 256, 256, 0, stream>>>(alpha, tau, omega, g);
    twiddle_kernel<<<8, 256, 0, stream>>>(tw);
    zero_kernel<<<64, 256, 0, stream>>>(feats, B_SZ * KM * FEAT);
    prep_w1<<<(KM * 4 * 32 * 32 + 255) / 256, 256, 0, stream>>>(W1, Wp1);
    prep_w2<<<(KM * 5 * 64 * 32 + 255) / 256, 256, 0, stream>>>(W2, Wp2);
    prep_w3<<<(KM * 3 * 64 * 64 + 255) / 256, 256, 0, stream>>>(W3, Wp3);
    fft_fwd_packed<<<NROWS / 2, 512, 0, stream>>>(x, tw, Xs);

    // all 4 modes in one k-batched inverse-FFT dispatch (coalesced planes)
    fft_inv_packed<<<dim3(NROWS / 2, KM), 512, 0, stream>>>(Xs, g, tw, modeU);

    for (int k = 0; k < KM; ++k) {
        conv1_mfma<<<dim3(T_LEN / 128, B_SZ), 256, 0, stream>>>(
            modeU + (size_t)k * B_SZ * 6 * T_LEN, Wp1 + (size_t)k * 4096,
            b1 + k * 32, g1 + k * 32, be1 + k * 32, h1bf);
        conv2_mfma<<<dim3(T_LEN / 128, B_SZ), 256, 0, stream>>>(
            h1bf, Wp2 + (size_t)k * 5 * 2048, b2 + k * 64, g2 + k * 64, be2 + k * 64, h2bf);
        conv3_mfma<<<dim3(T_LEN / 128, B_SZ), 256, 0, stream>>>(
            h2bf, Wp3 + (size_t)k * 3 * 64 * 64, b3 + k * 64, g3 + k * 64, be3 + k * 64,
            feats, k);
    }

    classifier_kernel<<<B_SZ, 128, 0, stream>>>(feats, Wc1, bc1, Wc2, bc2, (float*)d_out);
}

// Round 16
// 285.480 us; speedup vs baseline: 3.7966x; 1.0648x over previous
//
#include <hip/hip_runtime.h>
#include <math.h>

#define T_LEN 4096
#define NBINS 2049          // T/2+1
#define B_SZ 64
#define C_IN 12
#define KM 4
#define FEAT 64

typedef __attribute__((ext_vector_type(8))) short short8v;   // 8 bf16 (4 VGPRs)
typedef __attribute__((ext_vector_type(4))) float floatx4;

// fp32 -> bf16 with RNE
__device__ __forceinline__ unsigned short f2bf(float f)
{
    unsigned int u = __float_as_uint(f);
    u += 0x7FFFu + ((u >> 16) & 1u);
    return (unsigned short)(u >> 16);
}

// FFT LDS swizzle (complex-index involution): spreads radix-4 write strides
// across bank groups; consecutive-16 runs (all reads) stay conflict-free.
__device__ __forceinline__ int fphys(int i) { return i ^ ((i >> 4) & 15); }

// ---------------------------------------------------------------------------
// prep_all: one dispatch for twiddles (4096), gains (2049), feats-zero,
// and the three MFMA weight repacks (all layouts verified r11-r13).
// ---------------------------------------------------------------------------
__global__ void prep_all(const float* __restrict__ alpha,
                         const float* __restrict__ tau,
                         const float* __restrict__ omega,
                         const float* __restrict__ W1,
                         const float* __restrict__ W2,
                         const float* __restrict__ W3,
                         float2* __restrict__ tw4,
                         float* __restrict__ g,
                         float* __restrict__ feats,
                         unsigned short* __restrict__ Wp1,
                         unsigned short* __restrict__ Wp2,
                         unsigned short* __restrict__ Wp3)
{
    int gid = blockIdx.x * 256 + threadIdx.x;
    // [0, 4096): twiddle table tw4[i] = exp(-2*pi*i*i/4096)
    if (gid < 4096) {
        float ang = -(float)M_PI * (float)gid / 2048.0f;
        float sn, cs;
        sincosf(ang, &sn, &cs);
        tw4[gid] = make_float2(cs, sn);
        return;
    }
    gid -= 4096;
    // [0, 2049): gains
    if (gid < NBINS) {
        int f = gid;
        float freq = 0.5f * (float)f / 2048.0f;
        float a[4] = {0.f, 0.f, 0.f, 0.f};
        float s = 0.f, lamc = 0.f;
        for (int l = 0; l < 8; ++l) {
            for (int k = 0; k < 4; ++k) {
                float r = 1.f - (s - a[k]) + 0.5f * lamc;
                float d = freq - omega[k];
                float denom = 1.f + alpha[l * 4 + k] * d * d;
                float anew = r / denom;
                s += anew - a[k];
                a[k] = anew;
            }
            lamc += tau[l] * (1.f - s);
        }
        for (int k = 0; k < 4; ++k) g[k * NBINS + f] = a[k];
        return;
    }
    gid -= NBINS;
    // feats zero: 64*256
    if (gid < B_SZ * KM * FEAT) { feats[gid] = 0.f; return; }
    gid -= B_SZ * KM * FEAT;
    // prep_w1: 16384
    if (gid < KM * 4 * 32 * 32) {
        int i = gid;
        int kidx  = i & 31;
        int o     = (i >> 5) & 31;
        int dpair = (i >> 10) & 3;
        int k     = i >> 12;
        int d = dpair * 2 + (kidx >> 4);
        int c = kidx & 15;
        float v = (d < 7 && c < 12) ? W1[(((size_t)k * 32 + o) * 12 + c) * 7 + d] : 0.f;
        Wp1[(size_t)k * 4096 + dpair * 1024 + o * 32 + kidx] = f2bf(v);
        return;
    }
    gid -= KM * 4 * 32 * 32;
    // prep_w2: 40960
    if (gid < KM * 5 * 64 * 32) {
        int i = gid;
        int c = i & 31;
        int o = (i >> 5) & 63;
        int kd = i >> 11;
        int d = kd % 5, k = kd / 5;
        float v = W2[(((size_t)k * 64 + o) * 32 + c) * 5 + d];
        int sr = o >> 1;
        int q = (o & 1) * 4 + (c >> 3);
        int qp = q ^ (sr & 7);
        Wp2[(size_t)(k * 5 + d) * 2048 + sr * 64 + qp * 8 + (c & 7)] = f2bf(v);
        return;
    }
    gid -= KM * 5 * 64 * 32;
    // prep_w3: 49152
    if (gid < KM * 3 * 64 * 64) {
        int i = gid;
        int c = i & 63;
        int o = (i >> 6) & 63;
        int kd = i >> 12;
        int d = kd % 3, k = kd / 3;
        float v = W3[(((size_t)k * 64 + o) * 64 + c) * 3 + d];
        int blk = (c >> 3) ^ (o & 7);
        Wp3[(size_t)k * (3 * 64 * 64) + (d * 64 + o) * 64 + blk * 8 + (c & 7)] = f2bf(v);
        return;
    }
}

// ---------------------------------------------------------------------------
// Radix-4 Stockham, N=4096, 6 stages, swizzled LDS. syf=+1 fwd, -1 inv.
// Stage st: s = 4^st; item v in [0,1024): q = v & (s-1), p = v >> 2st;
// reads src[v + t*1024], twiddle idx1 = p << 2st, writes q + 4sp + t*s.
// ---------------------------------------------------------------------------
__device__ inline float2* fft_stages4(float2* bufA, float2* bufB,
                                      const float2* __restrict__ tw4, float syf)
{
    float2* src = bufA;
    float2* dst = bufB;
#pragma unroll
    for (int st = 0; st < 6; ++st) {
        const int sh = 2 * st;
        const int s = 1 << sh;
        for (int v = threadIdx.x; v < 1024; v += 512) {
            const int q = v & (s - 1);
            const int p = v >> sh;
            float2 a = src[fphys(v)];
            float2 b = src[fphys(v + 1024)];
            float2 c = src[fphys(v + 2048)];
            float2 d = src[fphys(v + 3072)];
            const int i1 = p << sh;
            float2 w1 = tw4[i1];
            float2 w2 = tw4[2 * i1];
            float2 w3 = tw4[3 * i1];
            float apcx = a.x + c.x, apcy = a.y + c.y;
            float amcx = a.x - c.x, amcy = a.y - c.y;
            float bpdx = b.x + d.x, bpdy = b.y + d.y;
            float sjx = -syf * (b.y - d.y);          // syf * i*(b-d)
            float sjy =  syf * (b.x - d.x);
            float2 x0 = make_float2(apcx + bpdx, apcy + bpdy);
            float t1x = amcx - sjx, t1y = amcy - sjy;
            float t2x = apcx - bpdx, t2y = apcy - bpdy;
            float t3x = amcx + sjx, t3y = amcy + sjy;
            float cs1 = w1.x, sn1 = syf * w1.y;
            float cs2 = w2.x, sn2 = syf * w2.y;
            float cs3 = w3.x, sn3 = syf * w3.y;
            float2 x1 = make_float2(cs1 * t1x - sn1 * t1y, cs1 * t1y + sn1 * t1x);
            float2 x2 = make_float2(cs2 * t2x - sn2 * t2y, cs2 * t2y + sn2 * t2x);
            float2 x3 = make_float2(cs3 * t3x - sn3 * t3y, cs3 * t3y + sn3 * t3x);
            const int ob = q + (p << (sh + 2));      // q + 4*s*p
            dst[fphys(ob)]         = x0;
            dst[fphys(ob + s)]     = x1;
            dst[fphys(ob + 2 * s)] = x2;
            dst[fphys(ob + 3 * s)] = x3;
        }
        __syncthreads();
        float2* tmp = src; src = dst; dst = tmp;
    }
    return src;   // 6 swaps -> result back in bufA
}

__global__ __launch_bounds__(512) void fft_fwd_packed(const float* __restrict__ x,
                                                      const float2* __restrict__ tw4,
                                                      float2* __restrict__ Xs)
{
    int rp = blockIdx.x;
    int b = rp / 6, c0 = (rp % 6) * 2;
    __shared__ float2 bufA[T_LEN];
    __shared__ float2 bufB[T_LEN];
    for (int t = threadIdx.x; t < T_LEN; t += 512) {
        const float* px = x + ((size_t)b * T_LEN + t) * C_IN + c0;
        bufA[fphys(t)] = make_float2(px[0], px[1]);
    }
    __syncthreads();
    float2* Z = fft_stages4(bufA, bufB, tw4, 1.f);
    size_t row = (size_t)b * C_IN + c0;
    for (int f = threadIdx.x; f <= 2048; f += 512) {
        float2 z  = Z[fphys(f)];
        float2 zm = Z[fphys((T_LEN - f) & (T_LEN - 1))];
        Xs[row * NBINS + f]       = make_float2(0.5f * (z.x + zm.x), 0.5f * (z.y - zm.y));
        Xs[(row + 1) * NBINS + f] = make_float2(0.5f * (z.y + zm.y), 0.5f * (zm.x - z.x));
    }
}

// ---------------------------------------------------------------------------
// Inverse FFT, k-batched. Output: contiguous bf16-pair planes
// mode[k][b][pair][t] (verified r15: coalesced, no write amplification).
// ---------------------------------------------------------------------------
__global__ __launch_bounds__(512) void fft_inv_packed(const float2* __restrict__ Xs,
                                                      const float* __restrict__ g,
                                                      const float2* __restrict__ tw4,
                                                      unsigned int* __restrict__ modeU)
{
    int rp = blockIdx.x;
    int kk = blockIdx.y;
    int b = rp / 6, pr = rp % 6;
    int c0 = pr * 2;
    size_t rowa = (size_t)b * C_IN + c0;
    __shared__ float2 bufA[T_LEN];
    __shared__ float2 bufB[T_LEN];
    const float* gk = g + kk * NBINS;
    for (int f = threadIdx.x; f < T_LEN; f += 512) {
        int fe = (f <= 2048) ? f : (T_LEN - f);
        float2 A  = Xs[rowa * NBINS + fe];
        float2 Bv = Xs[(rowa + 1) * NBINS + fe];
        float gv = gk[fe];
        if (f > 2048) { A.y = -A.y; Bv.y = -Bv.y; }
        bufA[fphys(f)] = make_float2(gv * (A.x - Bv.y), gv * (A.y + Bv.x));
    }
    __syncthreads();
    float2* z = fft_stages4(bufA, bufB, tw4, -1.f);
    const float invn = 1.f / (float)T_LEN;
    unsigned int* plane = modeU + (((size_t)kk * B_SZ + b) * 6 + pr) * T_LEN;
    for (int t = threadIdx.x; t < T_LEN; t += 512) {
        float2 zz = z[fphys(t)];
        unsigned int pk = (unsigned int)f2bf(zz.x * invn) |
                          ((unsigned int)f2bf(zz.y * invn) << 16);
        plane[t] = pk;
    }
}

// ---------------------------------------------------------------------------
// conv1 via MFMA bf16 (verified r15): staging from contiguous pair planes.
// ---------------------------------------------------------------------------
__global__ __launch_bounds__(256) void conv1_mfma(
    const unsigned int* __restrict__ pairsK,     // this k: [b][pair][t] uints
    const unsigned short* __restrict__ Wp1,      // this k slot: 4096 ush
    const float* __restrict__ bias,
    const float* __restrict__ gamma,
    const float* __restrict__ beta,
    unsigned short* __restrict__ h1bf)
{
    __shared__ __align__(16) char smem[4352 + 8192 + 8192];
    char* Xl  = smem;              // 34 superrows * 128B, t in [t0-4, t0+132)
    char* Wl  = smem + 4352;       // 8192B
    char* rep = smem + 4352 + 8192;

    const int b = blockIdx.y;
    const int t0 = blockIdx.x * 128;
    const int tid = threadIdx.x;
    const unsigned int* planes = pairsK + (size_t)b * 6 * T_LEN;
    const int sr0 = t0 >> 2;

    // stage X: 8 pair-slots x 34 4-t chunks
    for (int i = tid; i < 272; i += 256) {
        int p = i / 34;            // pair slot 0..7 (6,7 = zero channels)
        int tc = i % 34;
        int t_base = t0 - 4 + tc * 4;
        unsigned int vv[4] = {0u, 0u, 0u, 0u};
        if (p < 6) {
            const unsigned int* pl = planes + (size_t)p * T_LEN;
            if (t_base >= 0 && t_base + 3 < T_LEN) {
                uint4 v4 = *(const uint4*)(pl + t_base);
                vv[0] = v4.x; vv[1] = v4.y; vv[2] = v4.z; vv[3] = v4.w;
            } else {
#pragma unroll
                for (int e = 0; e < 4; ++e) {
                    int t = t_base + e;
                    vv[e] = (t >= 0 && t < T_LEN) ? pl[t] : 0u;
                }
            }
        }
        int cb = p >> 2, j = p & 3;
        int sr_g = t_base >> 2;            // all 4 elems share the superrow
        int ls = sr_g - sr0 + 1;           // 0..33
        int key = sr_g & 7;
#pragma unroll
        for (int e = 0; e < 4; ++e) {
            int q = e * 2 + cb;            // t&3 == e
            int qp = q ^ key;
            *(unsigned int*)(Xl + (size_t)ls * 128 + qp * 16 + j * 4) = vv[e];
        }
    }
    for (int i = tid; i < 512; i += 256)
        ((float4*)Wl)[i] = ((const float4*)Wp1)[i];
    __syncthreads();

    const int w  = tid >> 6;
    const int l  = tid & 63;
    const int lo = l & 15;
    const int hi = l >> 4;

    short8v Bf[4][2];
#pragma unroll
    for (int dp = 0; dp < 4; ++dp)
#pragma unroll
        for (int n = 0; n < 2; ++n) {
            int o = n * 16 + lo;
            Bf[dp][n] = *(const short8v*)(Wl + dp * 2048 + o * 64 + hi * 16);
        }

    floatx4 acc[2][2];
#pragma unroll
    for (int m = 0; m < 2; ++m)
#pragma unroll
        for (int n = 0; n < 2; ++n)
            acc[m][n] = (floatx4){0.f, 0.f, 0.f, 0.f};

#pragma unroll
    for (int dp = 0; dp < 4; ++dp)
#pragma unroll
        for (int m = 0; m < 2; ++m) {
            int t_in = t0 + w * 32 + m * 16 + lo + dp * 2 + (hi >> 1) - 3;
            int sr_g = t_in >> 2;
            int ls = sr_g - sr0 + 1;
            int q = (t_in & 3) * 2 + (hi & 1);
            int qp = q ^ (sr_g & 7);
            short8v Af = *(const short8v*)(Xl + (size_t)ls * 128 + qp * 16);
#pragma unroll
            for (int n = 0; n < 2; ++n)
                acc[m][n] = __builtin_amdgcn_mfma_f32_16x16x32_bf16(
                    Af, Bf[dp][n], acc[m][n], 0, 0, 0);
        }

    // epilogue: BN + ReLU, scatter into h1bf superrow format, flat store
    const float rs = 1.f / sqrtf(1.f + 1e-5f);
#pragma unroll
    for (int n = 0; n < 2; ++n) {
        int o = n * 16 + lo;
        float sc = gamma[o] * rs;
        float bb = fmaf(bias[o], sc, beta[o]);
#pragma unroll
        for (int m = 0; m < 2; ++m)
#pragma unroll
            for (int r = 0; r < 4; ++r) {
                float v = fmaxf(fmaf(acc[m][n][r], sc, bb), 0.f);
                int t_loc = w * 32 + m * 16 + 4 * hi + r;
                int q = (t_loc & 1) * 4 + (o >> 3);
                int qp = q ^ ((t_loc >> 1) & 7);
                *(unsigned short*)(rep + (size_t)(t_loc >> 1) * 128 + qp * 16 +
                                   (o & 7) * 2) = f2bf(v);
            }
    }
    __syncthreads();
    char* dst = (char*)h1bf + (size_t)b * (T_LEN * 64) + (size_t)t0 * 64;
    for (int i = tid; i < 512; i += 256)
        ((float4*)dst)[i] = ((float4*)rep)[i];
}

// ---------------------------------------------------------------------------
// conv2 via MFMA bf16 (verified r12).
// ---------------------------------------------------------------------------
__global__ __launch_bounds__(256) void conv2_mfma(
    const unsigned short* __restrict__ h1bf,
    const unsigned short* __restrict__ Wp2,    // 5 planes of 4096B
    const float* __restrict__ bias,
    const float* __restrict__ gamma,
    const float* __restrict__ beta,
    unsigned short* __restrict__ h2bf)
{
    __shared__ __align__(16) char smem[9216 + 20480 + 16384];
    char* Xl  = smem;
    char* Wl  = smem + 9216;
    char* rep = smem + 9216 + 20480;

    const int b = blockIdx.y;
    const int t0 = blockIdx.x * 128;
    const int tid = threadIdx.x;
    const char* src = (const char*)h1bf + (size_t)b * (T_LEN * 64);

    for (int i = tid; i < 576; i += 256) {
        int sr_loc = i >> 3;
        int qp = i & 7;
        int key = (sr_loc + 4) & 7;
        int q = qp ^ key;
        int t = (t0 - 8) + sr_loc * 2 + (q >> 2);
        float4 v = make_float4(0.f, 0.f, 0.f, 0.f);
        if (t >= 0 && t < T_LEN)
            v = *(const float4*)(src + (ptrdiff_t)(t0 - 8) * 64 + (size_t)i * 16);
        *(float4*)(Xl + (size_t)i * 16) = v;
    }
    for (int i = tid; i < 1280; i += 256)
        *(float4*)(Wl + (size_t)i * 16) = *(const float4*)((const char*)Wp2 + (size_t)i * 16);
    __syncthreads();

    const int w  = tid >> 6;
    const int l  = tid & 63;
    const int lo = l & 15;
    const int hi = l >> 4;

    short8v Bf[5][4];
#pragma unroll
    for (int d = 0; d < 5; ++d)
#pragma unroll
        for (int n = 0; n < 4; ++n) {
            int o = n * 16 + lo;
            int sr = o >> 1;
            int q = (o & 1) * 4 + hi;
            int qp = q ^ (sr & 7);
            Bf[d][n] = *(const short8v*)(Wl + (size_t)d * 4096 + sr * 128 + qp * 16);
        }

    floatx4 acc[2][4];
#pragma unroll
    for (int m = 0; m < 2; ++m)
#pragma unroll
        for (int n = 0; n < 4; ++n)
            acc[m][n] = (floatx4){0.f, 0.f, 0.f, 0.f};

#pragma unroll
    for (int d = 0; d < 5; ++d)
#pragma unroll
        for (int m = 0; m < 2; ++m) {
            int tl = w * 32 + m * 16 + lo + d + 6;
            int sr = tl >> 1;
            int q = (tl & 1) * 4 + hi;
            int qp = q ^ ((sr + 4) & 7);
            short8v Af = *(const short8v*)(Xl + (size_t)sr * 128 + qp * 16);
#pragma unroll
            for (int n = 0; n < 4; ++n)
                acc[m][n] = __builtin_amdgcn_mfma_f32_16x16x32_bf16(
                    Af, Bf[d][n], acc[m][n], 0, 0, 0);
        }

    const float rs = 1.f / sqrtf(1.f + 1e-5f);
#pragma unroll
    for (int n = 0; n < 4; ++n) {
        int o = n * 16 + lo;
        float sc = gamma[o] * rs;
        float bb = fmaf(bias[o], sc, beta[o]);
        int cq = o >> 3;
#pragma unroll
        for (int m = 0; m < 2; ++m)
#pragma unroll
            for (int r = 0; r < 4; ++r) {
                float v = fmaxf(fmaf(acc[m][n][r], sc, bb), 0.f);
                int trow = w * 32 + m * 16 + 4 * hi + r;
                *(unsigned short*)(rep + (size_t)trow * 128 +
                                   ((cq ^ (trow & 7)) * 16) + (o & 7) * 2) = f2bf(v);
            }
    }
    __syncthreads();
    char* dst = (char*)h2bf + (size_t)b * (T_LEN * 128) + (size_t)t0 * 128;
    for (int i = tid; i < 1024; i += 256)
        *(float4*)(dst + (size_t)i * 16) = *(float4*)(rep + (size_t)i * 16);
}

// ---------------------------------------------------------------------------
// conv3 via MFMA bf16 (verified r11): fused BN+ReLU+mean -> feats atomicAdd.
// ---------------------------------------------------------------------------
__global__ __launch_bounds__(256) void conv3_mfma(
    const unsigned short* __restrict__ h2bf,
    const unsigned short* __restrict__ Wp,
    const float* __restrict__ bias,
    const float* __restrict__ gamma,
    const float* __restrict__ beta,
    float* __restrict__ feats,
    int k_slot)
{
    __shared__ __align__(16) char smem[16640 + 24576];
    char* Xl = smem;
    char* Wl = smem + 16640;

    const int b = blockIdx.y;
    const int t0 = blockIdx.x * 128;
    const int tid = threadIdx.x;

    for (int i = tid; i < 1040; i += 256) {
        int row = i >> 3;
        int tg = t0 - 1 + row;
        float4 v = make_float4(0.f, 0.f, 0.f, 0.f);
        if (tg >= 0 && tg < T_LEN)
            v = *(const float4*)((const char*)h2bf + ((size_t)b * T_LEN + tg) * 128 + (i & 7) * 16);
        *(float4*)(Xl + (size_t)i * 16) = v;
    }
    for (int i = tid; i < 1536; i += 256)
        *(float4*)(Wl + (size_t)i * 16) = *(const float4*)((const char*)Wp + (size_t)i * 16);
    __syncthreads();

    const int w  = tid >> 6;
    const int l  = tid & 63;
    const int lo = l & 15;
    const int hi = l >> 4;

    short8v Bf[6][4];
#pragma unroll
    for (int d = 0; d < 3; ++d)
#pragma unroll
        for (int ch = 0; ch < 2; ++ch)
#pragma unroll
            for (int n = 0; n < 4; ++n) {
                int o = n * 16 + lo;
                int blk = (4 * ch + hi) ^ (o & 7);
                Bf[d * 2 + ch][n] =
                    *(const short8v*)(Wl + (size_t)(d * 64 + o) * 128 + blk * 16);
            }

    floatx4 acc[2][4];
#pragma unroll
    for (int m = 0; m < 2; ++m)
#pragma unroll
        for (int n = 0; n < 4; ++n)
            acc[m][n] = (floatx4){0.f, 0.f, 0.f, 0.f};

#pragma unroll
    for (int d = 0; d < 3; ++d)
#pragma unroll
        for (int ch = 0; ch < 2; ++ch) {
#pragma unroll
            for (int m = 0; m < 2; ++m) {
                int tl = w * 32 + m * 16 + lo + d;
                int blk = (4 * ch + hi) ^ ((tl - 1) & 7);
                short8v Af = *(const short8v*)(Xl + (size_t)tl * 128 + blk * 16);
#pragma unroll
                for (int n = 0; n < 4; ++n)
                    acc[m][n] = __builtin_amdgcn_mfma_f32_16x16x32_bf16(
                        Af, Bf[d * 2 + ch][n], acc[m][n], 0, 0, 0);
            }
        }

    const float rs = 1.f / sqrtf(1.f + 1e-5f);
#pragma unroll
    for (int n = 0; n < 4; ++n) {
        int o = n * 16 + lo;
        float sc = gamma[o] * rs;
        float bb = fmaf(bias[o], sc, beta[o]);
        float s = 0.f;
#pragma unroll
        for (int m = 0; m < 2; ++m)
#pragma unroll
            for (int r = 0; r < 4; ++r)
                s += fmaxf(fmaf(acc[m][n][r], sc, bb), 0.f);
        s += __shfl_xor(s, 16, 64);
        s += __shfl_xor(s, 32, 64);
        if (hi == 0)
            atomicAdd(&feats[b * (KM * FEAT) + k_slot * FEAT + o], s * (1.f / (float)T_LEN));
    }
}

// ---------------------------------------------------------------------------
// Classifier
// ---------------------------------------------------------------------------
__global__ __launch_bounds__(128) void classifier_kernel(const float* __restrict__ feats,
                                                         const float* __restrict__ Wc1,
                                                         const float* __restrict__ bc1,
                                                         const float* __restrict__ Wc2,
                                                         const float* __restrict__ bc2,
                                                         float* __restrict__ out)
{
    int b = blockIdx.x;
    int j = threadIdx.x;
    __shared__ float h[128];
    float acc = bc1[j];
    const float* fb = feats + b * 256;
    for (int i = 0; i < 256; ++i) acc = fmaf(fb[i], Wc1[j * 256 + i], acc);
    h[j] = fmaxf(acc, 0.f);
    __syncthreads();
    if (j < 10) {
        float acc2 = bc2[j];
        for (int i = 0; i < 128; ++i) acc2 = fmaf(h[i], Wc2[j * 128 + i], acc2);
        out[b * 10 + j] = acc2;
    }
}

extern "C" void kernel_launch(void* const* d_in, const int* in_sizes, int n_in,
                              void* d_out, int out_size, void* d_ws, size_t ws_size,
                              hipStream_t stream)
{
    const float* x     = (const float*)d_in[0];
    const float* alpha = (const float*)d_in[1];
    const float* tau   = (const float*)d_in[2];
    const float* omega = (const float*)d_in[3];
    const float* W1    = (const float*)d_in[4];
    const float* b1    = (const float*)d_in[5];
    const float* g1    = (const float*)d_in[6];
    const float* be1   = (const float*)d_in[7];
    const float* W2    = (const float*)d_in[8];
    const float* b2    = (const float*)d_in[9];
    const float* g2    = (const float*)d_in[10];
    const float* be2   = (const float*)d_in[11];
    const float* W3    = (const float*)d_in[12];
    const float* b3    = (const float*)d_in[13];
    const float* g3    = (const float*)d_in[14];
    const float* be3   = (const float*)d_in[15];
    const float* Wc1   = (const float*)d_in[16];
    const float* bc1   = (const float*)d_in[17];
    const float* Wc2   = (const float*)d_in[18];
    const float* bc2   = (const float*)d_in[19];

    const int NROWS = B_SZ * C_IN;   // 768
    float* ws = (float*)d_ws;
    float2* tw4  = (float2*)ws;                                  // 4096 c = 8192 floats
    float* g     = ws + 8192;                                    // 8196 floats
    float2* Xs   = (float2*)(ws + 8192 + 4 * NBINS);             // 3,147,264 floats
    unsigned int* modeU = (unsigned int*)(ws + 8192 + 4 * NBINS + (size_t)NROWS * NBINS * 2);
    // modeU: 4k * 64b * 6pair * 4096t uints = 25.2 MB
    unsigned short* h1bf = (unsigned short*)(modeU + (size_t)KM * B_SZ * 6 * T_LEN);
    unsigned short* h2bf = h1bf + (size_t)B_SZ * T_LEN * 32;
    float* feats = (float*)(h2bf + (size_t)B_SZ * T_LEN * 64);
    unsigned short* Wp1 = (unsigned short*)(feats + B_SZ * KM * FEAT);   // 16384 ush
    unsigned short* Wp2 = Wp1 + KM * 4096;                               // 40960 ush
    unsigned short* Wp3 = Wp2 + KM * 5 * 2048;                           // 49152 ush

    // one merged prep dispatch: tw4 + gains + feats-zero + 3 weight repacks
    const int PREP_TOT = 4096 + NBINS + B_SZ * KM * FEAT +
                         KM * 4 * 32 * 32 + KM * 5 * 64 * 32 + KM * 3 * 64 * 64;
    prep_all<<<(PREP_TOT + 255) / 256, 256, 0, stream>>>(
        alpha, tau, omega, W1, W2, W3, tw4, g, feats, Wp1, Wp2, Wp3);

    fft_fwd_packed<<<NROWS / 2, 512, 0, stream>>>(x, tw4, Xs);

    // all 4 modes in one k-batched inverse-FFT dispatch (coalesced planes)
    fft_inv_packed<<<dim3(NROWS / 2, KM), 512, 0, stream>>>(Xs, g, tw4, modeU);

    for (int k = 0; k < KM; ++k) {
        conv1_mfma<<<dim3(T_LEN / 128, B_SZ), 256, 0, stream>>>(
            modeU + (size_t)k * B_SZ * 6 * T_LEN, Wp1 + (size_t)k * 4096,
            b1 + k * 32, g1 + k * 32, be1 + k * 32, h1bf);
        conv2_mfma<<<dim3(T_LEN / 128, B_SZ), 256, 0, stream>>>(
            h1bf, Wp2 + (size_t)k * 5 * 2048, b2 + k * 64, g2 + k * 64, be2 + k * 64, h2bf);
        conv3_mfma<<<dim3(T_LEN / 128, B_SZ), 256, 0, stream>>>(
            h2bf, Wp3 + (size_t)k * 3 * 64 * 64, b3 + k * 64, g3 + k * 64, be3 + k * 64,
            feats, k);
    }

    classifier_kernel<<<B_SZ, 128, 0, stream>>>(feats, Wc1, bc1, Wc2, bc2, (float*)d_out);
}